// Round 6
// baseline (221.520 us; speedup 1.0000x reference)
//
#include <hip/hip_runtime.h>
#include <cstddef>
#include <cstdint>

typedef short  s16x8 __attribute__((ext_vector_type(8)));
typedef float  f32x4 __attribute__((ext_vector_type(4)));
typedef unsigned short u16x4 __attribute__((ext_vector_type(4)));

typedef __attribute__((address_space(1))) const void gas_void;
typedef __attribute__((address_space(3))) void las_void;

// ---------------- bf16 helpers ----------------
__device__ __forceinline__ unsigned short f2bh(float x) {
    union { float f; unsigned int u; } c; c.f = x;
    unsigned int r = c.u + 0x7fffu + ((c.u >> 16) & 1u);
    return (unsigned short)(r >> 16);
}
__device__ __forceinline__ float bh2f(unsigned short h) {
    union { unsigned int u; float f; } c; c.u = ((unsigned int)h) << 16;
    return c.f;
}
__device__ __forceinline__ f32x4 MF(s16x8 a, s16x8 b, f32x4 c) {
    return __builtin_amdgcn_mfma_f32_16x16x32_bf16(a, b, c, 0, 0, 0);
}
__device__ __forceinline__ void gload16(const unsigned short* g, unsigned short* l) {
    __builtin_amdgcn_global_load_lds((gas_void*)g, (las_void*)l, 16, 0, 0);
}

// ---------------- vec region offsets (floats) ----------------
static constexpr size_t OFF_VIS  = 0;
static constexpr size_t OFF_SEM  = 512;
static constexpr size_t OFF_GCN  = 1024;
static constexpr size_t OFF_S512 = 1536;
static constexpr size_t OFF_VROW = 2048;
static constexpr size_t OFF_X    = 3072;
static constexpr size_t OFF_Y3   = 4096;
static constexpr size_t OFF_H3   = 8192;
// fallback big buffers (floats, absolute in ws)
static constexpr size_t OFF_BUF0 = 16384;
static constexpr size_t OFF_BUF1 = OFF_BUF0 + 4194304;
static constexpr size_t OFF_BUF2 = OFF_BUF1 + 4194304;

// ---------------- fast-path ws layout (bytes) ----------------
static constexpr size_t F_ADJH  = 0;                          // 4096*4096*2 = 33554432
static constexpr size_t F_EMB_H = F_ADJH + 33554432;          // 4096*320*2 = 2621440
static constexpr size_t F_EMB_L = F_EMB_H + 2621440;
static constexpr size_t F_SW_H  = F_EMB_L + 2621440;          // 512*320*2 = 327680
static constexpr size_t F_SW_L  = F_SW_H + 327680;
static constexpr size_t F_W1T_H = F_SW_L + 327680;            // 1024*512*2 = 1048576
static constexpr size_t F_W1T_L = F_W1T_H + 1048576;
static constexpr size_t F_W2T_H = F_W1T_L + 1048576;          // 1024*1024*2 = 2097152
static constexpr size_t F_EMT   = F_W2T_H + 2097152;          // 512*4096*2 = 4194304
static constexpr size_t F_P1_H  = F_EMT + 4194304;            // 4096*512*2
static constexpr size_t F_P1_L  = F_P1_H + 4194304;
static constexpr size_t F_H1    = F_P1_L + 4194304;           // 4096*1024*2 = 8388608
static constexpr size_t F_Y2T   = F_H1 + 8388608;             // 1024*4096*2 = 8388608
// P1 split-K f32 partials: 2 * 4096*512*4 = 16777216, ALIASED over H1+Y2T
static constexpr size_t F_P1F   = F_H1;
static constexpr size_t F_Y3P   = F_Y2T + 8388608;            // 16*4096*4 (region 524288)
static constexpr size_t F_VEC   = F_Y3P + 524288;             // 12288 floats
static constexpr size_t FAST_WS = F_VEC + 49152;              // ~73.2 MB

// ---------------- block reduction ----------------
__device__ inline float blockReduceSum256(float v) {
    #pragma unroll
    for (int o = 32; o > 0; o >>= 1) v += __shfl_down(v, o, 64);
    __shared__ float red[4];
    int w = threadIdx.x >> 6;
    if ((threadIdx.x & 63) == 0) red[w] = v;
    __syncthreads();
    if (threadIdx.x == 0) v = red[0] + red[1] + red[2] + red[3];
    return v;
}

// ---------------- vec3 body ----------------
__device__ __forceinline__ void vec3_body(int b,
                            const float* __restrict__ frames,
                            const float* __restrict__ scores,
                            const float* __restrict__ word_embed,
                            const float* __restrict__ visual_W, const float* __restrict__ visual_b,
                            const float* __restrict__ semantic_W, const float* __restrict__ semantic_b,
                            const float* __restrict__ score_W, const float* __restrict__ score_b,
                            float* __restrict__ vec) {
    const float* x; const float* W; const float* bias; float* out; int K; int row;
    if (b < 512)       { row = b;        x = frames;     W = visual_W;   bias = visual_b;   out = vec + OFF_VIS;  K = 8192; }
    else if (b < 1024) { row = b - 512;  x = word_embed; W = semantic_W; bias = semantic_b; out = vec + OFF_SEM;  K = 300;  }
    else               { row = b - 1024; x = scores;     W = score_W;    bias = score_b;    out = vec + OFF_S512; K = 1000; }
    const float* wr = W + (size_t)row * K;
    float s = 0.f;
    for (int k = threadIdx.x; k < K; k += 256) s += wr[k] * x[k];
    s = blockReduceSum256(s);
    if (threadIdx.x == 0) out[row] = fmaxf(s + bias[row], 0.f);
}

// ---------------- small kernels ----------------
__global__ void vec3_kernel(const float* __restrict__ frames,
                            const float* __restrict__ scores,
                            const float* __restrict__ word_embed,
                            const float* __restrict__ visual_W, const float* __restrict__ visual_b,
                            const float* __restrict__ semantic_W, const float* __restrict__ semantic_b,
                            const float* __restrict__ score_W, const float* __restrict__ score_b,
                            float* __restrict__ vec) {
    vec3_body(blockIdx.x, frames, scores, word_embed, visual_W, visual_b,
              semantic_W, semantic_b, score_W, score_b, vec);
}

// vrow[j] = sum_k s512[k] * gc1_W[k, j]; grid 8 x 256 threads, k split in halves
__global__ void vrow_kernel(const float* __restrict__ gc1_W, float* __restrict__ vec) {
    __shared__ float part[128];
    const float* s512 = vec + OFF_S512;
    int jl = threadIdx.x & 127;
    int j = blockIdx.x * 128 + jl;
    int kh = threadIdx.x >> 7;
    float s = 0.f;
    #pragma unroll 4
    for (int k = kh * 256; k < kh * 256 + 256; k++)
        s += s512[k] * gc1_W[(size_t)k * 1024 + j];
    if (kh) part[jl] = s;
    __syncthreads();
    if (!kh) vec[OFF_VROW + j] = s + part[jl];
}

__global__ void y3_kernel(const float* __restrict__ H2, const float* __restrict__ gc3_W,
                          float* __restrict__ vec) {
    int i = blockIdx.x;
    const float* r = H2 + (size_t)i * 1024;
    float s = 0.f;
    for (int k = threadIdx.x; k < 1024; k += 256) s += r[k] * gc3_W[k];
    s = blockReduceSum256(s);
    if (threadIdx.x == 0) vec[OFF_Y3 + i] = s;
}

// y3 partial reduction (fast path): vec[Y3+i] = sum_p y3p[p][i], 16 partials
__global__ void y3red_kernel(const float* __restrict__ y3p, float* __restrict__ vec) {
    int i = blockIdx.x * 256 + threadIdx.x;
    float s = 0.f;
    #pragma unroll
    for (int p = 0; p < 16; p++) s += y3p[(size_t)p * 4096 + i];
    vec[OFF_Y3 + i] = s;
}

// h3 from bf16 adj
__global__ void h3b_kernel(const unsigned short* __restrict__ adj_h,
                           const float* __restrict__ gc3_b, float* __restrict__ vec) {
    int i = blockIdx.x;
    const u16x4* rp = (const u16x4*)(adj_h + (size_t)i * 4096);
    const float* y3 = vec + OFF_Y3;
    float s = 0.f;
    for (int c = threadIdx.x; c < 1024; c += 256) {
        u16x4 v = rp[c];
        int k0 = c * 4;
        s += bh2f(v[0]) * y3[k0] + bh2f(v[1]) * y3[k0 + 1]
           + bh2f(v[2]) * y3[k0 + 2] + bh2f(v[3]) * y3[k0 + 3];
    }
    s = blockReduceSum256(s);
    if (threadIdx.x == 0) vec[OFF_H3 + i] = fmaxf(s + gc3_b[0], 0.f);
}

__global__ void h3_kernel(const float* __restrict__ adj, const float* __restrict__ gc3_b,
                          float* __restrict__ vec) {
    int i = blockIdx.x;
    const float* r = adj + (size_t)i * 4096;
    const float* y3 = vec + OFF_Y3;
    float s = 0.f;
    for (int k = threadIdx.x; k < 4096; k += 256) s += r[k] * y3[k];
    s = blockReduceSum256(s);
    if (threadIdx.x == 0) vec[OFF_H3 + i] = fmaxf(s + gc3_b[0], 0.f);
}

__global__ void gcn_kernel(const float* __restrict__ gcn512_W, const float* __restrict__ gcn512_b,
                           float* __restrict__ vec) {
    int j = blockIdx.x;
    const float* r = gcn512_W + (size_t)j * 4096;
    const float* h3 = vec + OFF_H3;
    float s = 0.f;
    for (int k = threadIdx.x; k < 4096; k += 256) s += r[k] * h3[k];
    s = blockReduceSum256(s);
    if (threadIdx.x == 0) vec[OFF_GCN + j] = fmaxf(s + gcn512_b[j], 0.f);
}

__global__ void x_kernel(const float* __restrict__ hidden_W, const float* __restrict__ hidden_b,
                         float* __restrict__ vec) {
    int j = blockIdx.x;
    const float* r = hidden_W + (size_t)j * 1536;
    const float* joint = vec;
    float s = 0.f;
    for (int k = threadIdx.x; k < 1536; k += 256) s += r[k] * joint[k];
    s = blockReduceSum256(s);
    if (threadIdx.x == 0) vec[OFF_X + j] = fmaxf(s + hidden_b[j], 0.f);
}

__global__ void out_kernel(const float* __restrict__ vec,
                           const float* __restrict__ critic_W, const float* __restrict__ critic_b,
                           const float* __restrict__ actor_W, const float* __restrict__ actor_b,
                           float* __restrict__ out) {
    const float* xv = vec + OFF_X;
    int w = threadIdx.x >> 6, l = threadIdx.x & 63;
    if (w >= 7) return;
    const float* row = (w == 0) ? critic_W : actor_W + (size_t)(w - 1) * 512;
    float s = 0.f;
    for (int q = l; q < 512; q += 64) s += xv[q] * row[q];
    #pragma unroll
    for (int o = 32; o > 0; o >>= 1) s += __shfl_down(s, o, 64);
    if (l == 0) out[w] = s + ((w == 0) ? critic_b[0] : actor_b[w - 1]);
}

// combine P1 split-K partials -> hi/lo bf16
__global__ void combine_p1_kernel(const float* __restrict__ p1f,
                                  unsigned short* __restrict__ hi, unsigned short* __restrict__ lo) {
    size_t i = (size_t)blockIdx.x * 256 + threadIdx.x;    // float4 index over 524288
    float4 a = ((const float4*)p1f)[i];
    float4 b = ((const float4*)(p1f + 2097152))[i];
    u16x4 hv, lv;
    float v0 = a.x + b.x, v1 = a.y + b.y, v2 = a.z + b.z, v3 = a.w + b.w;
    hv[0] = f2bh(v0); lv[0] = f2bh(v0 - bh2f(hv[0]));
    hv[1] = f2bh(v1); lv[1] = f2bh(v1 - bh2f(hv[1]));
    hv[2] = f2bh(v2); lv[2] = f2bh(v2 - bh2f(hv[2]));
    hv[3] = f2bh(v3); lv[3] = f2bh(v3 - bh2f(hv[3]));
    *(u16x4*)(hi + i * 4) = hv;
    *(u16x4*)(lo + i * 4) = lv;
}

// ---------------- fused prep kernel: all converts + vec3 ----------------
__global__ void prep_kernel(const float* __restrict__ adj,
                            const float* __restrict__ all_embeds,
                            const float* __restrict__ semantic_W,
                            const float* __restrict__ gc1_W,
                            const float* __restrict__ gc2_W,
                            const float* __restrict__ frames,
                            const float* __restrict__ scores,
                            const float* __restrict__ word_embed,
                            const float* __restrict__ visual_W, const float* __restrict__ visual_b,
                            const float* __restrict__ semantic_b,
                            const float* __restrict__ score_W, const float* __restrict__ score_b,
                            unsigned short* __restrict__ adj_h,
                            unsigned short* __restrict__ emb_h, unsigned short* __restrict__ emb_l,
                            unsigned short* __restrict__ sw_h, unsigned short* __restrict__ sw_l,
                            unsigned short* __restrict__ w1t_h, unsigned short* __restrict__ w1t_l,
                            unsigned short* __restrict__ w2t_h,
                            float* __restrict__ vec) {
    __shared__ float tile[32][33];
    const int b = blockIdx.x, t = threadIdx.x;
    if (b < 16384) {
        size_t i = (size_t)b * 256 + t;
        float4 v = ((const float4*)adj)[i];
        u16x4 h; h[0] = f2bh(v.x); h[1] = f2bh(v.y); h[2] = f2bh(v.z); h[3] = f2bh(v.w);
        *(u16x4*)(adj_h + i * 4) = h;
    } else if (b < 16384 + 5120) {
        size_t i = (size_t)(b - 16384) * 256 + t;   // over 4096*320
        int r = (int)(i / 320), c = (int)(i % 320);
        float v = (c < 300) ? all_embeds[(size_t)r * 300 + c] : 0.f;
        unsigned short h = f2bh(v);
        emb_h[i] = h; emb_l[i] = f2bh(v - bh2f(h));
    } else if (b < 16384 + 5120 + 640) {
        size_t i = (size_t)(b - 16384 - 5120) * 256 + t;   // over 512*320
        int r = (int)(i / 320), c = (int)(i % 320);
        float v = (c < 300) ? semantic_W[(size_t)r * 300 + c] : 0.f;
        unsigned short h = f2bh(v);
        sw_h[i] = h; sw_l[i] = f2bh(v - bh2f(h));
    } else if (b < 16384 + 5120 + 640 + 512) {
        // w1T: src = gc1_W[512:,:] f32 [K=512, N=1024] -> [N,K] hi+lo
        int l2 = b - 16384 - 5120 - 640;
        const float* src = gc1_W + (size_t)512 * 1024;
        int kb = (l2 & 15) * 32, nb = (l2 >> 4) * 32;
        int tx = t & 31, ty = t >> 5;
        #pragma unroll
        for (int i = 0; i < 32; i += 8)
            tile[ty + i][tx] = src[(size_t)(kb + ty + i) * 1024 + nb + tx];
        __syncthreads();
        #pragma unroll
        for (int i = 0; i < 32; i += 8) {
            int n = nb + ty + i, k = kb + tx;
            float v = tile[tx][ty + i];
            unsigned short h = f2bh(v);
            w1t_h[(size_t)n * 512 + k] = h;
            w1t_l[(size_t)n * 512 + k] = f2bh(v - bh2f(h));
        }
    } else if (b < 16384 + 5120 + 640 + 512 + 1024) {
        // w2T: gc2_W f32 [1024,1024] -> [N,K] hi
        int l2 = b - 16384 - 5120 - 640 - 512;
        int kb = (l2 & 31) * 32, nb = (l2 >> 5) * 32;
        int tx = t & 31, ty = t >> 5;
        #pragma unroll
        for (int i = 0; i < 32; i += 8)
            tile[ty + i][tx] = gc2_W[(size_t)(kb + ty + i) * 1024 + nb + tx];
        __syncthreads();
        #pragma unroll
        for (int i = 0; i < 32; i += 8) {
            int n = nb + ty + i, k = kb + tx;
            w2t_h[(size_t)n * 1024 + k] = f2bh(tile[tx][ty + i]);
        }
    } else {
        vec3_body(b - (16384 + 5120 + 640 + 512 + 1024), frames, scores, word_embed,
                  visual_W, visual_b, semantic_W, semantic_b, score_W, score_b, vec);
    }
}

// ---------------- staging helpers ----------------
template<int NCHP, int NJ>
__device__ __forceinline__ void stg_mat(const unsigned short* __restrict__ src, int ld, int r0,
                                        int k0, unsigned short* dst, int t) {
    #pragma unroll
    for (int j = 0; j < NJ; j++) {
        int c = j * 256 + t;
        int p = c / NCHP;
        int idx = c % NCHP;
        int row = idx >> 2;
        int gg = (idx & 3) ^ ((row >> 1) & 3);
        gload16(src + (size_t)(r0 + row) * ld + (k0 + p * 32 + gg * 8),
                dst + (size_t)(j * 256 + (t & ~63)) * 8);
    }
}

template<int ROWS>
__device__ __forceinline__ s16x8 rfrag(const unsigned short* rb, int row, int p, int g4) {
    int byte = (p * ROWS + row) * 64 + ((g4 ^ ((row >> 1) & 3)) << 4);
    return *(const s16x8*)((const char*)rb + byte);
}

// ---------------- 4-wave PROD=3 MFMA GEMM (for #3 emT and #5 h1) ----------------
// C[M,N] = A[M,K] @ B^T; split hi/lo on both sides (3 products).
// WMODE: 3 hi C[m][n]; 4 hi C^T[n][m] (ldc=M)
template<int BM, int BK, int WMODE, int RELU>
__global__ __launch_bounds__(256) void mfma_gemm(
    const unsigned short* __restrict__ Ah, const unsigned short* __restrict__ Al,
    const unsigned short* __restrict__ Bh, const unsigned short* __restrict__ Bl,
    int K, int lda, int ldb,
    unsigned short* __restrict__ Ch, int ldc,
    const float* __restrict__ bias, const float* __restrict__ bias2)
{
    constexpr int A_USH = BM * BK;
    constexpr int B_USH = 64 * BK;
    constexpr int A_CH  = A_USH / 8;
    constexpr int B_CH  = B_USH / 8;
    constexpr int SLOT  = 2 * (A_USH + B_USH);
    constexpr int L     = ((A_CH + B_CH) / 256) * 2;
    constexpr int FM    = BM / 32;
    __shared__ unsigned short lds[3 * SLOT];

    const int t = threadIdx.x;
    const int w = t >> 6, l = t & 63;
    const int r = l & 15, g4 = l >> 4;
    const int wr = (w >> 1) * (BM / 2);
    const int wc = (w & 1) * 32;

    const int gx = gridDim.x;
    const int nwg = gx * gridDim.y;
    int flat = blockIdx.y * gx + blockIdx.x;
    int swz = (flat & 7) * (nwg >> 3) + (flat >> 3);
    const int col0 = (swz % gx) * 64;
    const int row0 = (swz / gx) * BM;

    f32x4 acc[FM][2];
    #pragma unroll
    for (int a = 0; a < FM; a++)
        #pragma unroll
        for (int b = 0; b < 2; b++) acc[a][b] = (f32x4){0.f, 0.f, 0.f, 0.f};

    auto stage = [&](int slot, int k0) {
        unsigned short* base = lds + slot * SLOT;
        stg_mat<BM * 4, A_CH / 256>(Ah, lda, row0, k0, base, t);
        stg_mat<256,    B_CH / 256>(Bh, ldb, col0, k0, base + A_USH, t);
        stg_mat<256,    B_CH / 256>(Bl, ldb, col0, k0, base + A_USH + B_USH, t);
        stg_mat<BM * 4, A_CH / 256>(Al, lda, row0, k0, base + A_USH + 2 * B_USH, t);
    };

    const int T = K / BK;
    stage(0, 0);
    stage(1, BK);

    for (int tt = 0; tt < T; ++tt) {
        __builtin_amdgcn_s_barrier();
        if (tt + 2 < T) {
            stage((tt + 2) % 3, (tt + 2) * BK);
            if constexpr (L == 4) asm volatile("s_waitcnt vmcnt(8)" ::: "memory");
            else                  asm volatile("s_waitcnt vmcnt(12)" ::: "memory");
        } else if (tt + 1 < T) {
            if constexpr (L == 4) asm volatile("s_waitcnt vmcnt(4)" ::: "memory");
            else                  asm volatile("s_waitcnt vmcnt(6)" ::: "memory");
        } else {
            asm volatile("s_waitcnt vmcnt(0)" ::: "memory");
        }
        __builtin_amdgcn_s_barrier();

        const unsigned short* base = lds + (tt % 3) * SLOT;
        #pragma unroll
        for (int kk = 0; kk < BK / 32; kk++) {
            s16x8 a[FM], bb[2], alr[FM], blr[2];
            #pragma unroll
            for (int f = 0; f < FM; f++) a[f] = rfrag<BM>(base, wr + f * 16 + r, kk, g4);
            #pragma unroll
            for (int f = 0; f < 2; f++) bb[f] = rfrag<64>(base + A_USH, wc + f * 16 + r, kk, g4);
            #pragma unroll
            for (int f = 0; f < 2; f++) blr[f] = rfrag<64>(base + A_USH + B_USH, wc + f * 16 + r, kk, g4);
            #pragma unroll
            for (int f = 0; f < FM; f++) alr[f] = rfrag<BM>(base + A_USH + 2 * B_USH, wr + f * 16 + r, kk, g4);
            __builtin_amdgcn_s_setprio(1);
            #pragma unroll
            for (int fm = 0; fm < FM; fm++)
                #pragma unroll
                for (int fn = 0; fn < 2; fn++) {
                    acc[fm][fn] = MF(a[fm], bb[fn], acc[fm][fn]);
                    acc[fm][fn] = MF(a[fm], blr[fn], acc[fm][fn]);
                    acc[fm][fn] = MF(alr[fm], bb[fn], acc[fm][fn]);
                }
            __builtin_amdgcn_s_setprio(0);
        }
    }

    #pragma unroll
    for (int fn = 0; fn < 2; fn++) {
        int n = col0 + wc + fn * 16 + r;
        float bn = bias ? bias[n] : 0.f;
        if (bias2) bn += bias2[n];
        #pragma unroll
        for (int fm = 0; fm < FM; fm++) {
            int m0 = row0 + wr + fm * 16 + g4 * 4;
            f32x4 v = acc[fm][fn];
            if constexpr (WMODE == 4) {
                u16x4 hv;
                #pragma unroll
                for (int i = 0; i < 4; i++) {
                    float x = v[i] + bn;
                    if (RELU) x = fmaxf(x, 0.f);
                    hv[i] = f2bh(x);
                }
                *(u16x4*)(Ch + (size_t)n * ldc + m0) = hv;
            } else {  // WMODE 3
                #pragma unroll
                for (int i = 0; i < 4; i++) {
                    float x = v[i] + bn;
                    if (RELU) x = fmaxf(x, 0.f);
                    Ch[(size_t)(m0 + i) * ldc + n] = f2bh(x);
                }
            }
        }
    }
}

// ---------------- 4-wave K-SPLIT hi-only MFMA GEMM, tile 128x64, wave 64x64 ----------------
// Waves: q = w&1 (row half), h = w>>1 (K half). Each wave: full 64x64 output for its K half.
// LDS slot 24 KB (A 2x128x32k + B 2x64x32k), ring-3 = 72 KB -> 2 blocks/CU = 2 waves/SIMD.
// End: K-halves combined via LDS (f32, stride 65 -> <=2-way conflicts).
// WMODE: 4 hi C^T[n][m] (ldc=M); 5 fused relu+bias then y3 partial; 6 f32 C[m][n]
template<int WMODE, int RELU, int SPLITK>
__global__ __launch_bounds__(256) void mfma_gemmq(
    const unsigned short* __restrict__ Ah,
    const unsigned short* __restrict__ Bh,
    int K, int lda, int ldb,
    unsigned short* __restrict__ Ch, float* __restrict__ Cf, int ldc,
    const float* __restrict__ bias,
    const float* __restrict__ w3, float* __restrict__ y3p)
{
    constexpr int A_USH = 128 * 64;           // 2 panels x 128 rows x 32k
    constexpr int B_USH = 64 * 64;            // 2 panels x 64 rows x 32k
    constexpr int SLOT  = A_USH + B_USH;      // 12288 ush = 24 KB
    __shared__ unsigned short lds[3 * SLOT];  // 72 KB

    const int t = threadIdx.x;
    const int w = t >> 6, l = t & 63;
    const int r = l & 15, g4 = l >> 4;
    const int q = w & 1;     // row half (0: rows 0-63, 1: rows 64-127)
    const int h = w >> 1;    // K half

    const int gx = gridDim.x;
    const int nwg = gx * gridDim.y;
    int flat = blockIdx.y * gx + blockIdx.x;
    int swz = (flat & 7) * (nwg >> 3) + (flat >> 3);
    const int col0 = (swz % gx) * 64;
    const int row0 = (swz / gx) * 128;

    const int Khalf = K >> 1;

    if constexpr (SPLITK) {
        int z = blockIdx.z;
        Ah += (size_t)z * K;
        Bh += (size_t)z * K;
        Cf += (size_t)z * (size_t)nwg * 8192;
    }

    f32x4 acc[4][4];
    #pragma unroll
    for (int a = 0; a < 4; a++)
        #pragma unroll
        for (int b = 0; b < 4; b++) acc[a][b] = (f32x4){0.f, 0.f, 0.f, 0.f};

    auto stage = [&](int slot, int k0) {   // k0 = tt*32 within each half
        unsigned short* base = lds + slot * SLOT;
        #pragma unroll
        for (int j = 0; j < 4; j++) {      // A: 1024 chunks (2 panels x 128 rows x 4)
            int c = j * 256 + t;
            int p = c >> 9;
            int idx = c & 511;
            int row = idx >> 2;
            int gg = (idx & 3) ^ ((row >> 1) & 3);
            gload16(Ah + (size_t)(row0 + row) * lda + (p * Khalf + k0 + gg * 8),
                    base + (size_t)(j * 256 + (t & ~63)) * 8);
        }
        #pragma unroll
        for (int j = 0; j < 2; j++) {      // B: 512 chunks (2 panels x 64 rows x 4)
            int c = j * 256 + t;
            int p = c >> 8;
            int idx = c & 255;
            int row = idx >> 2;
            int gg = (idx & 3) ^ ((row >> 1) & 3);
            gload16(Bh + (size_t)(col0 + row) * ldb + (p * Khalf + k0 + gg * 8),
                    base + A_USH + (size_t)(j * 256 + (t & ~63)) * 8);
        }
    };

    const int T = Khalf >> 5;
    stage(0, 0);
    stage(1, 32);

    for (int tt = 0; tt < T; ++tt) {
        __builtin_amdgcn_s_barrier();
        if (tt + 2 < T) {
            stage((tt + 2) % 3, (tt + 2) * 32);
            asm volatile("s_waitcnt vmcnt(12)" ::: "memory");
        } else if (tt + 1 < T) {
            asm volatile("s_waitcnt vmcnt(6)" ::: "memory");
        } else {
            asm volatile("s_waitcnt vmcnt(0)" ::: "memory");
        }
        __builtin_amdgcn_s_barrier();

        const unsigned short* base = lds + (tt % 3) * SLOT;
        s16x8 a[4], bb[4];
        #pragma unroll
        for (int f = 0; f < 4; f++) a[f] = rfrag<128>(base, q * 64 + f * 16 + r, h, g4);
        #pragma unroll
        for (int f = 0; f < 4; f++) bb[f] = rfrag<64>(base + A_USH, f * 16 + r, h, g4);
        __builtin_amdgcn_s_setprio(1);
        #pragma unroll
        for (int fm = 0; fm < 4; fm++)
            #pragma unroll
            for (int fn = 0; fn < 4; fn++)
                acc[fm][fn] = MF(a[fm], bb[fn], acc[fm][fn]);
        __builtin_amdgcn_s_setprio(0);
    }

    // ---- combine K halves via LDS (f32, stride 65) ----
    float* lf = (float*)lds;
    __syncthreads();                       // all waves done reading LDS tiles
    if (h == 1) {
        float* tb = lf + q * 4160;
        #pragma unroll
        for (int fn = 0; fn < 4; fn++) {
            int nl = fn * 16 + r;
            #pragma unroll
            for (int fm = 0; fm < 4; fm++) {
                int ml = fm * 16 + g4 * 4;
                #pragma unroll
                for (int i = 0; i < 4; i++)
                    tb[(ml + i) * 65 + nl] = acc[fm][fn][i];
            }
        }
    }
    __syncthreads();
    if (h == 1) return;

    {
        float* tb = lf + q * 4160;
        #pragma unroll
        for (int fn = 0; fn < 4; fn++) {
            int nl = fn * 16 + r;
            #pragma unroll
            for (int fm = 0; fm < 4; fm++) {
                int ml = fm * 16 + g4 * 4;
                #pragma unroll
                for (int i = 0; i < 4; i++)
                    acc[fm][fn][i] += tb[(ml + i) * 65 + nl];
            }
        }
    }

    // epilogue (waves 0,1 only; C/D: col = lane&15, row = 4*(lane>>4)+i)
    if constexpr (WMODE == 5) {
        float yacc[4][4];
        #pragma unroll
        for (int fm = 0; fm < 4; fm++)
            #pragma unroll
            for (int i = 0; i < 4; i++) yacc[fm][i] = 0.f;
        #pragma unroll
        for (int fn = 0; fn < 4; fn++) {
            int n = col0 + fn * 16 + r;
            float bn = bias[n];
            float wn = w3[n];
            #pragma unroll
            for (int fm = 0; fm < 4; fm++) {
                f32x4 v = acc[fm][fn];
                #pragma unroll
                for (int i = 0; i < 4; i++) {
                    float x = fmaxf(v[i] + bn, 0.f);
                    yacc[fm][i] += x * wn;
                }
            }
        }
        int slot = col0 >> 6;   // 16 slots
        #pragma unroll
        for (int fm = 0; fm < 4; fm++)
            #pragma unroll
            for (int i = 0; i < 4; i++) {
                float v = yacc[fm][i];
                v += __shfl_xor(v, 1, 64);
                v += __shfl_xor(v, 2, 64);
                v += __shfl_xor(v, 4, 64);
                v += __shfl_xor(v, 8, 64);
                if ((l & 15) == 0)
                    y3p[(size_t)slot * 4096 + row0 + q * 64 + fm * 16 + g4 * 4 + i] = v;
            }
    } else {
        #pragma unroll
        for (int fn = 0; fn < 4; fn++) {
            int n = col0 + fn * 16 + r;
            float bn = bias ? bias[n] : 0.f;
            #pragma unroll
            for (int fm = 0; fm < 4; fm++) {
                int m0 = row0 + q * 64 + fm * 16 + g4 * 4;
                f32x4 v = acc[fm][fn];
                if constexpr (WMODE == 4) {
                    u16x4 hv;
                    #pragma unroll
                    for (int i = 0; i < 4; i++) {
                        float x = v[i] + bn;
                        if (RELU) x = fmaxf(x, 0.f);
                        hv[i] = f2bh(x);
                    }
                    *(u16x4*)(Ch + (size_t)n * ldc + m0) = hv;
                } else {  // WMODE 6: f32
                    #pragma unroll
                    for (int i = 0; i < 4; i++) {
                        float x = v[i] + bn;
                        if (RELU) x = fmaxf(x, 0.f);
                        Cf[(size_t)(m0 + i) * ldc + n] = x;
                    }
                }
            }
        }
    }
}

// ---------------- fallback f32 tiled GEMM (round-1, proven) ----------------
template<int TRANSB>
__global__ __launch_bounds__(256) void gemm_f32_128(
    const float* __restrict__ A, const float* __restrict__ B, float* __restrict__ C,
    int M, int N, int K, int lda, int ldb,
    const float* __restrict__ bias, const float* __restrict__ vrow, int do_relu)
{
    constexpr int BM = 128, BN = 128, BK = 16;
    __shared__ float As[BK][BM + 4];
    __shared__ float Bs[BK][BN + 4];
    const int t = threadIdx.x;
    const int w = t >> 6, l = t & 63;
    const int cx = (w & 1) * 8 + (l & 7);
    const int cy = (w >> 1) * 8 + (l >> 3);
    const int row0 = blockIdx.y * BM;
    const int col0 = blockIdx.x * BN;

    float acc[8][8];
    #pragma unroll
    for (int i = 0; i < 8; i++)
        #pragma unroll
        for (int j = 0; j < 8; j++) acc[i][j] = 0.f;

    const int ka = t & 15;
    const int ma = t >> 4;

    for (int k0 = 0; k0 < K; k0 += BK) {
        #pragma unroll
        for (int i = 0; i < 8; i++) {
            int m = ma + i * 16;
            int gk = k0 + ka;
            float v = 0.f;
            if (gk < K) v = A[(size_t)(row0 + m) * lda + gk];
            As[ka][m] = v;
        }
        if (TRANSB) {
            #pragma unroll
            for (int i = 0; i < 8; i++) {
                int n = ma + i * 16;
                int gk = k0 + ka;
                float v = 0.f;
                if (gk < K) v = B[(size_t)(col0 + n) * ldb + gk];
                Bs[ka][n] = v;
            }
        } else {
            const int nb = t & 127;
            const int kb = t >> 7;
            #pragma unroll
            for (int i = 0; i < 8; i++) {
                int kk = kb + i * 2;
                int gk = k0 + kk;
                float v = 0.f;
                if (gk < K) v = B[(size_t)gk * ldb + col0 + nb];
                Bs[kk][nb] = v;
            }
        }
        __syncthreads();
        #pragma unroll
        for (int kk = 0; kk < BK; kk++) {
            float a[8], bb[8];
            *(float4*)&a[0]  = *(const float4*)&As[kk][cy * 8];
            *(float4*)&a[4]  = *(const float4*)&As[kk][cy * 8 + 4];
            *(float4*)&bb[0] = *(const float4*)&Bs[kk][cx * 8];
            *(float4*)&bb[4] = *(const float4*)&Bs[kk][cx * 8 + 4];
            #pragma unroll
            for (int i = 0; i < 8; i++)
                #pragma unroll
                for (int j = 0; j < 8; j++)
                    acc[i][j] = fmaf(a[i], bb[j], acc[i][j]);
        }
        __syncthreads();
    }

    #pragma unroll
    for (int i = 0; i < 8; i++) {
        int rr = row0 + cy * 8 + i;
        float vv[8];
        #pragma unroll
        for (int j = 0; j < 8; j++) {
            int c = col0 + cx * 8 + j;
            float v = acc[i][j];
            if (vrow) v += vrow[c];
            if (bias) v += bias[c];
            if (do_relu) v = fmaxf(v, 0.f);
            vv[j] = v;
        }
        float* cp = C + (size_t)rr * N + col0 + cx * 8;
        *(float4*)cp       = *(float4*)&vv[0];
        *(float4*)(cp + 4) = *(float4*)&vv[4];
    }
}

// ---------------- host launcher ----------------
extern "C" void kernel_launch(void* const* d_in, const int* in_sizes, int n_in,
                              void* d_out, int out_size, void* d_ws, size_t ws_size,
                              hipStream_t stream) {
    const float* frames     = (const float*)d_in[0];
    const float* scores     = (const float*)d_in[1];
    const float* word_embed = (const float*)d_in[2];
    const float* all_embeds = (const float*)d_in[3];
    const float* adj        = (const float*)d_in[4];
    const float* visual_W   = (const float*)d_in[5];
    const float* visual_b   = (const float*)d_in[6];
    const float* semantic_W = (const float*)d_in[7];
    const float* semantic_b = (const float*)d_in[8];
    const float* score_W    = (const float*)d_in[9];
    const float* score_b    = (const float*)d_in[10];
    const float* gc1_W      = (const float*)d_in[11];
    const float* gc1_b      = (const float*)d_in[12];
    const float* gc2_W      = (const float*)d_in[13];
    const float* gc2_b      = (const float*)d_in[14];
    const float* gc3_W      = (const float*)d_in[15];
    const float* gc3_b      = (const float*)d_in[16];
    const float* gcn512_W   = (const float*)d_in[17];
    const float* gcn512_b   = (const float*)d_in[18];
    const float* hidden_W   = (const float*)d_in[19];
    const float* hidden_b   = (const float*)d_in[20];
    const float* critic_W   = (const float*)d_in[21];
    const float* critic_b   = (const float*)d_in[22];
    const float* actor_W    = (const float*)d_in[23];
    const float* actor_b    = (const float*)d_in[24];

    float* out = (float*)d_out;

    if (ws_size >= FAST_WS) {
        char* wsb = (char*)d_ws;
        unsigned short* adj_h = (unsigned short*)(wsb + F_ADJH);
        unsigned short* emb_h = (unsigned short*)(wsb + F_EMB_H);
        unsigned short* emb_l = (unsigned short*)(wsb + F_EMB_L);
        unsigned short* sw_h  = (unsigned short*)(wsb + F_SW_H);
        unsigned short* sw_l  = (unsigned short*)(wsb + F_SW_L);
        unsigned short* w1t_h = (unsigned short*)(wsb + F_W1T_H);
        unsigned short* w1t_l = (unsigned short*)(wsb + F_W1T_L);
        unsigned short* w2t_h = (unsigned short*)(wsb + F_W2T_H);
        unsigned short* emT   = (unsigned short*)(wsb + F_EMT);
        unsigned short* p1_h  = (unsigned short*)(wsb + F_P1_H);
        unsigned short* p1_l  = (unsigned short*)(wsb + F_P1_L);
        unsigned short* h1    = (unsigned short*)(wsb + F_H1);
        unsigned short* y2t   = (unsigned short*)(wsb + F_Y2T);
        float*          p1f   = (float*)(wsb + F_P1F);   // aliases H1+Y2T (dead then)
        float*          y3p   = (float*)(wsb + F_Y3P);
        float*          vec   = (float*)(wsb + F_VEC);

        // 1. prep: all converts + vec3
        prep_kernel<<<16384 + 5120 + 640 + 512 + 1024 + 1536, 256, 0, stream>>>(
            adj, all_embeds, semantic_W, gc1_W, gc2_W,
            frames, scores, word_embed, visual_W, visual_b, semantic_b, score_W, score_b,
            adj_h, emb_h, emb_l, sw_h, sw_l, w1t_h, w1t_l, w2t_h, vec);
        // 2. vrow = s512 @ gc1_W[:512,:]
        vrow_kernel<<<8, 256, 0, stream>>>(gc1_W, vec);
        // 3. emT = relu(all_embeds @ semantic_W^T + b)^T  hi [512,4096], K=320, PROD=3
        mfma_gemm<64, 32, 4, 1><<<dim3(8, 64), 256, 0, stream>>>(
            emb_h, emb_l, sw_h, sw_l, 320, 320, 320,
            emT, 4096, semantic_b, nullptr);
        // 4. P1 partials = adj @ em  f32, split-K x2  [4096,512]
        mfma_gemmq<6, 0, 1><<<dim3(8, 32, 2), 256, 0, stream>>>(
            adj_h, emT, 2048, 4096, 4096,
            nullptr, p1f, 512, nullptr, nullptr, nullptr);
        // 4b. combine partials -> p1 hi/lo
        combine_p1_kernel<<<2048, 256, 0, stream>>>(p1f, p1_h, p1_l);
        // 5. h1 = relu(P1 @ W1' + vrow + b1)  hi [4096,1024], K=512, PROD=3
        mfma_gemm<128, 32, 3, 1><<<dim3(16, 32), 256, 0, stream>>>(
            p1_h, p1_l, w1t_h, w1t_l, 512, 512, 512,
            h1, 1024, gc1_b, vec + OFF_VROW);
        // 6. y2t = (h1 @ gc2_W)^T  hi [1024,4096], K=1024
        mfma_gemmq<4, 0, 0><<<dim3(16, 32), 256, 0, stream>>>(
            h1, w2t_h, 1024, 1024, 1024,
            y2t, nullptr, 4096, nullptr, nullptr, nullptr);
        // 7. fused: H2 = relu(adj @ Y2 + b2); y3 partials = H2 @ gc3_W  (K=4096)
        mfma_gemmq<5, 1, 0><<<dim3(16, 32), 256, 0, stream>>>(
            adj_h, y2t, 4096, 4096, 4096,
            nullptr, nullptr, 0, gc2_b, gc3_W, y3p);
        // 8. y3 = sum of 16 partials
        y3red_kernel<<<16, 256, 0, stream>>>(y3p, vec);
        // 9-12. tail
        h3b_kernel<<<4096, 256, 0, stream>>>(adj_h, gc3_b, vec);
        gcn_kernel<<<512, 256, 0, stream>>>(gcn512_W, gcn512_b, vec);
        x_kernel<<<512, 256, 0, stream>>>(hidden_W, hidden_b, vec);
        out_kernel<<<1, 512, 0, stream>>>(vec, critic_W, critic_b, actor_W, actor_b, out);
    } else {
        // fallback f32 path (round-1, proven within 50.4 MB)
        float* ws = (float*)d_ws;
        float* em = ws + OFF_BUF0;
        float* Y1 = ws + OFF_BUF1;
        float* H1 = ws + OFF_BUF2;
        float* Y2 = ws + OFF_BUF1;
        float* H2 = ws + OFF_BUF0;

        vec3_kernel<<<1536, 256, 0, stream>>>(frames, scores, word_embed,
                                              visual_W, visual_b, semantic_W, semantic_b,
                                              score_W, score_b, ws);
        vrow_kernel<<<8, 256, 0, stream>>>(gc1_W, ws);
        gemm_f32_128<1><<<dim3(512 / 128, 4096 / 128), 256, 0, stream>>>(
            all_embeds, semantic_W, em, 4096, 512, 300, 300, 300, semantic_b, nullptr, 1);
        gemm_f32_128<0><<<dim3(1024 / 128, 4096 / 128), 256, 0, stream>>>(
            em, gc1_W + (size_t)512 * 1024, Y1, 4096, 1024, 512, 512, 1024,
            nullptr, ws + OFF_VROW, 0);
        gemm_f32_128<0><<<dim3(1024 / 128, 4096 / 128), 256, 0, stream>>>(
            adj, Y1, H1, 4096, 1024, 4096, 4096, 1024, gc1_b, nullptr, 1);
        gemm_f32_128<0><<<dim3(1024 / 128, 4096 / 128), 256, 0, stream>>>(
            H1, gc2_W, Y2, 4096, 1024, 1024, 1024, 1024, nullptr, nullptr, 0);
        gemm_f32_128<0><<<dim3(1024 / 128, 4096 / 128), 256, 0, stream>>>(
            adj, Y2, H2, 4096, 1024, 4096, 4096, 1024, gc2_b, nullptr, 1);
        y3_kernel<<<4096, 256, 0, stream>>>(H2, gc3_W, ws);
        h3_kernel<<<4096, 256, 0, stream>>>(adj, gc3_b, ws);
        gcn_kernel<<<512, 256, 0, stream>>>(gcn512_W, gcn512_b, ws);
        x_kernel<<<512, 256, 0, stream>>>(hidden_W, hidden_b, ws);
        out_kernel<<<1, 512, 0, stream>>>(ws, critic_W, critic_b, actor_W, actor_b, out);
    }

    (void)in_sizes; (void)n_in; (void)out_size;
}

// Round 7
// 192.929 us; speedup vs baseline: 1.1482x; 1.1482x over previous
//
#include <hip/hip_runtime.h>
#include <cstddef>
#include <cstdint>

typedef short  s16x8 __attribute__((ext_vector_type(8)));
typedef float  f32x4 __attribute__((ext_vector_type(4)));
typedef unsigned short u16x4 __attribute__((ext_vector_type(4)));

typedef __attribute__((address_space(1))) const void gas_void;
typedef __attribute__((address_space(3))) void las_void;

// ---------------- bf16 helpers ----------------
__device__ __forceinline__ unsigned short f2bh(float x) {
    union { float f; unsigned int u; } c; c.f = x;
    unsigned int r = c.u + 0x7fffu + ((c.u >> 16) & 1u);
    return (unsigned short)(r >> 16);
}
__device__ __forceinline__ float bh2f(unsigned short h) {
    union { unsigned int u; float f; } c; c.u = ((unsigned int)h) << 16;
    return c.f;
}
__device__ __forceinline__ f32x4 MF(s16x8 a, s16x8 b, f32x4 c) {
    return __builtin_amdgcn_mfma_f32_16x16x32_bf16(a, b, c, 0, 0, 0);
}
__device__ __forceinline__ void gload16(const unsigned short* g, unsigned short* l) {
    __builtin_amdgcn_global_load_lds((gas_void*)g, (las_void*)l, 16, 0, 0);
}

// ---------------- vec region offsets (floats) ----------------
static constexpr size_t OFF_VIS  = 0;
static constexpr size_t OFF_SEM  = 512;
static constexpr size_t OFF_GCN  = 1024;
static constexpr size_t OFF_S512 = 1536;
static constexpr size_t OFF_VROW = 2048;
static constexpr size_t OFF_X    = 3072;
static constexpr size_t OFF_Y3   = 4096;
static constexpr size_t OFF_H3   = 8192;
// fallback big buffers (floats, absolute in ws)
static constexpr size_t OFF_BUF0 = 16384;
static constexpr size_t OFF_BUF1 = OFF_BUF0 + 4194304;
static constexpr size_t OFF_BUF2 = OFF_BUF1 + 4194304;

// ---------------- fast-path ws layout (bytes) ----------------
static constexpr size_t F_ADJH  = 0;                          // 4096*4096*2 = 33554432
static constexpr size_t F_EMB_H = F_ADJH + 33554432;          // 4096*320*2 = 2621440
static constexpr size_t F_EMB_L = F_EMB_H + 2621440;
static constexpr size_t F_SW_H  = F_EMB_L + 2621440;          // 512*320*2 = 327680
static constexpr size_t F_SW_L  = F_SW_H + 327680;
static constexpr size_t F_W1T_H = F_SW_L + 327680;            // 1024*512*2 = 1048576
static constexpr size_t F_W1T_L = F_W1T_H + 1048576;
static constexpr size_t F_W2T_H = F_W1T_L + 1048576;          // 1024*1024*2 = 2097152
static constexpr size_t F_EMT   = F_W2T_H + 2097152;          // 512*4096*2 = 4194304
static constexpr size_t F_P1_H  = F_EMT + 4194304;            // 4096*512*2
static constexpr size_t F_P1_L  = F_P1_H + 4194304;
static constexpr size_t F_H1    = F_P1_L + 4194304;           // 4096*1024*2 = 8388608
static constexpr size_t F_Y2T   = F_H1 + 8388608;             // 1024*4096*2 = 8388608
// P1 split-K f32 partials: 2 * 4096*512*4 = 16777216, ALIASED over H1+Y2T
// (written by GEMM #4, consumed by combine; h1 and y2t are written only later)
static constexpr size_t F_P1F   = F_H1;
static constexpr size_t F_Y3P   = F_Y2T + 8388608;            // 32*4096*4 = 524288
static constexpr size_t F_VEC   = F_Y3P + 524288;             // 12288 floats
static constexpr size_t FAST_WS = F_VEC + 49152;              // ~73.2 MB

// ---------------- block reduction ----------------
__device__ inline float blockReduceSum256(float v) {
    #pragma unroll
    for (int o = 32; o > 0; o >>= 1) v += __shfl_down(v, o, 64);
    __shared__ float red[4];
    int w = threadIdx.x >> 6;
    if ((threadIdx.x & 63) == 0) red[w] = v;
    __syncthreads();
    if (threadIdx.x == 0) v = red[0] + red[1] + red[2] + red[3];
    return v;
}

// ---------------- vec3 body ----------------
__device__ __forceinline__ void vec3_body(int b,
                            const float* __restrict__ frames,
                            const float* __restrict__ scores,
                            const float* __restrict__ word_embed,
                            const float* __restrict__ visual_W, const float* __restrict__ visual_b,
                            const float* __restrict__ semantic_W, const float* __restrict__ semantic_b,
                            const float* __restrict__ score_W, const float* __restrict__ score_b,
                            float* __restrict__ vec) {
    const float* x; const float* W; const float* bias; float* out; int K; int row;
    if (b < 512)       { row = b;        x = frames;     W = visual_W;   bias = visual_b;   out = vec + OFF_VIS;  K = 8192; }
    else if (b < 1024) { row = b - 512;  x = word_embed; W = semantic_W; bias = semantic_b; out = vec + OFF_SEM;  K = 300;  }
    else               { row = b - 1024; x = scores;     W = score_W;    bias = score_b;    out = vec + OFF_S512; K = 1000; }
    const float* wr = W + (size_t)row * K;
    float s = 0.f;
    for (int k = threadIdx.x; k < K; k += 256) s += wr[k] * x[k];
    s = blockReduceSum256(s);
    if (threadIdx.x == 0) out[row] = fmaxf(s + bias[row], 0.f);
}

// ---------------- small kernels ----------------
__global__ void vec3_kernel(const float* __restrict__ frames,
                            const float* __restrict__ scores,
                            const float* __restrict__ word_embed,
                            const float* __restrict__ visual_W, const float* __restrict__ visual_b,
                            const float* __restrict__ semantic_W, const float* __restrict__ semantic_b,
                            const float* __restrict__ score_W, const float* __restrict__ score_b,
                            float* __restrict__ vec) {
    vec3_body(blockIdx.x, frames, scores, word_embed, visual_W, visual_b,
              semantic_W, semantic_b, score_W, score_b, vec);
}

// vrow[j] = sum_k s512[k] * gc1_W[k, j]
__global__ void vrow_kernel(const float* __restrict__ gc1_W, float* __restrict__ vec) {
    __shared__ float part[128];
    const float* s512 = vec + OFF_S512;
    int jl = threadIdx.x & 127;
    int j = blockIdx.x * 128 + jl;
    int kh = threadIdx.x >> 7;
    float s = 0.f;
    #pragma unroll 4
    for (int k = kh * 256; k < kh * 256 + 256; k++)
        s += s512[k] * gc1_W[(size_t)k * 1024 + j];
    if (kh) part[jl] = s;
    __syncthreads();
    if (!kh) vec[OFF_VROW + j] = s + part[jl];
}

__global__ void y3_kernel(const float* __restrict__ H2, const float* __restrict__ gc3_W,
                          float* __restrict__ vec) {
    int i = blockIdx.x;
    const float* r = H2 + (size_t)i * 1024;
    float s = 0.f;
    for (int k = threadIdx.x; k < 1024; k += 256) s += r[k] * gc3_W[k];
    s = blockReduceSum256(s);
    if (threadIdx.x == 0) vec[OFF_Y3 + i] = s;
}

// y3 partial reduction: vec[Y3+i] = sum over 32 partials
__global__ void y3red_kernel(const float* __restrict__ y3p, float* __restrict__ vec) {
    int i = blockIdx.x * 256 + threadIdx.x;
    float s = 0.f;
    #pragma unroll
    for (int p = 0; p < 32; p++) s += y3p[(size_t)p * 4096 + i];
    vec[OFF_Y3 + i] = s;
}

// h3 from bf16 adj
__global__ void h3b_kernel(const unsigned short* __restrict__ adj_h,
                           const float* __restrict__ gc3_b, float* __restrict__ vec) {
    int i = blockIdx.x;
    const u16x4* rp = (const u16x4*)(adj_h + (size_t)i * 4096);
    const float* y3 = vec + OFF_Y3;
    float s = 0.f;
    for (int c = threadIdx.x; c < 1024; c += 256) {
        u16x4 v = rp[c];
        int k0 = c * 4;
        s += bh2f(v[0]) * y3[k0] + bh2f(v[1]) * y3[k0 + 1]
           + bh2f(v[2]) * y3[k0 + 2] + bh2f(v[3]) * y3[k0 + 3];
    }
    s = blockReduceSum256(s);
    if (threadIdx.x == 0) vec[OFF_H3 + i] = fmaxf(s + gc3_b[0], 0.f);
}

__global__ void h3_kernel(const float* __restrict__ adj, const float* __restrict__ gc3_b,
                          float* __restrict__ vec) {
    int i = blockIdx.x;
    const float* r = adj + (size_t)i * 4096;
    const float* y3 = vec + OFF_Y3;
    float s = 0.f;
    for (int k = threadIdx.x; k < 4096; k += 256) s += r[k] * y3[k];
    s = blockReduceSum256(s);
    if (threadIdx.x == 0) vec[OFF_H3 + i] = fmaxf(s + gc3_b[0], 0.f);
}

__global__ void gcn_kernel(const float* __restrict__ gcn512_W, const float* __restrict__ gcn512_b,
                           float* __restrict__ vec) {
    int j = blockIdx.x;
    const float* r = gcn512_W + (size_t)j * 4096;
    const float* h3 = vec + OFF_H3;
    float s = 0.f;
    for (int k = threadIdx.x; k < 4096; k += 256) s += r[k] * h3[k];
    s = blockReduceSum256(s);
    if (threadIdx.x == 0) vec[OFF_GCN + j] = fmaxf(s + gcn512_b[j], 0.f);
}

__global__ void x_kernel(const float* __restrict__ hidden_W, const float* __restrict__ hidden_b,
                         float* __restrict__ vec) {
    int j = blockIdx.x;
    const float* r = hidden_W + (size_t)j * 1536;
    const float* joint = vec;
    float s = 0.f;
    for (int k = threadIdx.x; k < 1536; k += 256) s += r[k] * joint[k];
    s = blockReduceSum256(s);
    if (threadIdx.x == 0) vec[OFF_X + j] = fmaxf(s + hidden_b[j], 0.f);
}

__global__ void out_kernel(const float* __restrict__ vec,
                           const float* __restrict__ critic_W, const float* __restrict__ critic_b,
                           const float* __restrict__ actor_W, const float* __restrict__ actor_b,
                           float* __restrict__ out) {
    const float* xv = vec + OFF_X;
    int w = threadIdx.x >> 6, l = threadIdx.x & 63;
    if (w >= 7) return;
    const float* row = (w == 0) ? critic_W : actor_W + (size_t)(w - 1) * 512;
    float s = 0.f;
    for (int q = l; q < 512; q += 64) s += xv[q] * row[q];
    #pragma unroll
    for (int o = 32; o > 0; o >>= 1) s += __shfl_down(s, o, 64);
    if (l == 0) out[w] = s + ((w == 0) ? critic_b[0] : actor_b[w - 1]);
}

// combine P1 split-K partials -> hi/lo bf16
__global__ void combine_p1_kernel(const float* __restrict__ p1f,
                                  unsigned short* __restrict__ hi, unsigned short* __restrict__ lo) {
    size_t i = (size_t)blockIdx.x * 256 + threadIdx.x;    // float4 index over 524288
    float4 a = ((const float4*)p1f)[i];
    float4 b = ((const float4*)(p1f + 2097152))[i];
    u16x4 hv, lv;
    float v0 = a.x + b.x, v1 = a.y + b.y, v2 = a.z + b.z, v3 = a.w + b.w;
    hv[0] = f2bh(v0); lv[0] = f2bh(v0 - bh2f(hv[0]));
    hv[1] = f2bh(v1); lv[1] = f2bh(v1 - bh2f(hv[1]));
    hv[2] = f2bh(v2); lv[2] = f2bh(v2 - bh2f(hv[2]));
    hv[3] = f2bh(v3); lv[3] = f2bh(v3 - bh2f(hv[3]));
    *(u16x4*)(hi + i * 4) = hv;
    *(u16x4*)(lo + i * 4) = lv;
}

// ---------------- fused prep kernel: all converts + vec3 ----------------
__global__ void prep_kernel(const float* __restrict__ adj,
                            const float* __restrict__ all_embeds,
                            const float* __restrict__ semantic_W,
                            const float* __restrict__ gc1_W,
                            const float* __restrict__ gc2_W,
                            const float* __restrict__ frames,
                            const float* __restrict__ scores,
                            const float* __restrict__ word_embed,
                            const float* __restrict__ visual_W, const float* __restrict__ visual_b,
                            const float* __restrict__ semantic_b,
                            const float* __restrict__ score_W, const float* __restrict__ score_b,
                            unsigned short* __restrict__ adj_h,
                            unsigned short* __restrict__ emb_h, unsigned short* __restrict__ emb_l,
                            unsigned short* __restrict__ sw_h, unsigned short* __restrict__ sw_l,
                            unsigned short* __restrict__ w1t_h, unsigned short* __restrict__ w1t_l,
                            unsigned short* __restrict__ w2t_h,
                            float* __restrict__ vec) {
    __shared__ float tile[32][33];
    const int b = blockIdx.x, t = threadIdx.x;
    if (b < 16384) {
        size_t i = (size_t)b * 256 + t;
        float4 v = ((const float4*)adj)[i];
        u16x4 h; h[0] = f2bh(v.x); h[1] = f2bh(v.y); h[2] = f2bh(v.z); h[3] = f2bh(v.w);
        *(u16x4*)(adj_h + i * 4) = h;
    } else if (b < 16384 + 5120) {
        size_t i = (size_t)(b - 16384) * 256 + t;   // over 4096*320
        int r = (int)(i / 320), c = (int)(i % 320);
        float v = (c < 300) ? all_embeds[(size_t)r * 300 + c] : 0.f;
        unsigned short h = f2bh(v);
        emb_h[i] = h; emb_l[i] = f2bh(v - bh2f(h));
    } else if (b < 16384 + 5120 + 640) {
        size_t i = (size_t)(b - 16384 - 5120) * 256 + t;   // over 512*320
        int r = (int)(i / 320), c = (int)(i % 320);
        float v = (c < 300) ? semantic_W[(size_t)r * 300 + c] : 0.f;
        unsigned short h = f2bh(v);
        sw_h[i] = h; sw_l[i] = f2bh(v - bh2f(h));
    } else if (b < 16384 + 5120 + 640 + 512) {
        // w1T: src = gc1_W[512:,:] f32 [K=512, N=1024] -> [N,K] hi+lo
        int l2 = b - 16384 - 5120 - 640;
        const float* src = gc1_W + (size_t)512 * 1024;
        int kb = (l2 & 15) * 32, nb = (l2 >> 4) * 32;
        int tx = t & 31, ty = t >> 5;
        #pragma unroll
        for (int i = 0; i < 32; i += 8)
            tile[ty + i][tx] = src[(size_t)(kb + ty + i) * 1024 + nb + tx];
        __syncthreads();
        #pragma unroll
        for (int i = 0; i < 32; i += 8) {
            int n = nb + ty + i, k = kb + tx;
            float v = tile[tx][ty + i];
            unsigned short h = f2bh(v);
            w1t_h[(size_t)n * 512 + k] = h;
            w1t_l[(size_t)n * 512 + k] = f2bh(v - bh2f(h));
        }
    } else if (b < 16384 + 5120 + 640 + 512 + 1024) {
        // w2T: gc2_W f32 [1024,1024] -> [N,K] hi
        int l2 = b - 16384 - 5120 - 640 - 512;
        int kb = (l2 & 31) * 32, nb = (l2 >> 5) * 32;
        int tx = t & 31, ty = t >> 5;
        #pragma unroll
        for (int i = 0; i < 32; i += 8)
            tile[ty + i][tx] = gc2_W[(size_t)(kb + ty + i) * 1024 + nb + tx];
        __syncthreads();
        #pragma unroll
        for (int i = 0; i < 32; i += 8) {
            int n = nb + ty + i, k = kb + tx;
            w2t_h[(size_t)n * 1024 + k] = f2bh(tile[tx][ty + i]);
        }
    } else {
        vec3_body(b - (16384 + 5120 + 640 + 512 + 1024), frames, scores, word_embed,
                  visual_W, visual_b, semantic_W, semantic_b, score_W, score_b, vec);
    }
}

// ---------------- staging helpers ----------------
template<int NCHP, int NJ>
__device__ __forceinline__ void stg_mat(const unsigned short* __restrict__ src, int ld, int r0,
                                        int k0, unsigned short* dst, int t) {
    #pragma unroll
    for (int j = 0; j < NJ; j++) {
        int c = j * 256 + t;
        int p = c / NCHP;
        int idx = c % NCHP;
        int row = idx >> 2;
        int gg = (idx & 3) ^ ((row >> 1) & 3);
        gload16(src + (size_t)(r0 + row) * ld + (k0 + p * 32 + gg * 8),
                dst + (size_t)(j * 256 + (t & ~63)) * 8);
    }
}

template<int ROWS>
__device__ __forceinline__ s16x8 rfrag(const unsigned short* rb, int row, int p, int g4) {
    int byte = (p * ROWS + row) * 64 + ((g4 ^ ((row >> 1) & 3)) << 4);
    return *(const s16x8*)((const char*)rb + byte);
}

// ---------------- 4-wave MFMA GEMM (round-4 proven structure) ----------------
// C[M,N] = A[M,K] @ B^T ; A,B bf16, K-contiguous rows (NT). Tile BM x 64, wave (BM/2) x 32.
// PROD: 1 = Ah*Bh ; 3 = Ah*Bh + Ah*Bl + Al*Bh
// WMODE: 3 hi C[m][n]; 4 hi C^T[n][m] (ldc=M); 5 fused relu+bias then y3 partials; 6 f32 C[m][n]
// SPLITK: blockIdx.z selects K-chunk; Ah/Bh advance z*K; Cf advances z*M*N.
template<int BM, int BK, int PROD, int WMODE, int RELU, int SPLITK>
__global__ __launch_bounds__(256) void mfma_g(
    const unsigned short* __restrict__ Ah, const unsigned short* __restrict__ Al,
    const unsigned short* __restrict__ Bh, const unsigned short* __restrict__ Bl,
    int K, int lda, int ldb,
    unsigned short* __restrict__ Ch, float* __restrict__ Cf, int ldc,
    const float* __restrict__ bias, const float* __restrict__ bias2,
    const float* __restrict__ w3, float* __restrict__ y3p)
{
    constexpr int A_USH = BM * BK;
    constexpr int B_USH = 64 * BK;
    constexpr int A_CH  = A_USH / 8;
    constexpr int B_CH  = B_USH / 8;
    constexpr int SLOT  = (PROD == 3) ? 2 * (A_USH + B_USH) : (A_USH + B_USH);
    constexpr int L     = ((A_CH + B_CH) / 256) * ((PROD == 3) ? 2 : 1);
    constexpr int FM    = BM / 32;
    __shared__ unsigned short lds[3 * SLOT];

    const int t = threadIdx.x;
    const int w = t >> 6, l = t & 63;
    const int r = l & 15, g4 = l >> 4;
    const int wr = (w >> 1) * (BM / 2);
    const int wc = (w & 1) * 32;

    const int gx = gridDim.x;
    const int nwg = gx * gridDim.y;
    int flat = blockIdx.y * gx + blockIdx.x;
    int swz = (flat & 7) * (nwg >> 3) + (flat >> 3);
    const int col0 = (swz % gx) * 64;
    const int row0 = (swz / gx) * BM;

    if constexpr (SPLITK) {
        int z = blockIdx.z;
        Ah += (size_t)z * K;
        Bh += (size_t)z * K;
        Cf += (size_t)z * (size_t)nwg * (BM * 64);
    }

    f32x4 acc[FM][2];
    #pragma unroll
    for (int a = 0; a < FM; a++)
        #pragma unroll
        for (int b = 0; b < 2; b++) acc[a][b] = (f32x4){0.f, 0.f, 0.f, 0.f};

    auto stage = [&](int slot, int k0) {
        unsigned short* base = lds + slot * SLOT;
        stg_mat<BM * 4, A_CH / 256>(Ah, lda, row0, k0, base, t);
        stg_mat<256,    B_CH / 256>(Bh, ldb, col0, k0, base + A_USH, t);
        if constexpr (PROD == 3) {
            stg_mat<256,    B_CH / 256>(Bl, ldb, col0, k0, base + A_USH + B_USH, t);
            stg_mat<BM * 4, A_CH / 256>(Al, lda, row0, k0, base + A_USH + 2 * B_USH, t);
        }
    };

    const int T = K / BK;
    stage(0, 0);
    stage(1, BK);

    for (int tt = 0; tt < T; ++tt) {
        __builtin_amdgcn_s_barrier();
        if (tt + 2 < T) {
            stage((tt + 2) % 3, (tt + 2) * BK);
            if constexpr (L == 4) asm volatile("s_waitcnt vmcnt(8)" ::: "memory");
            else                  asm volatile("s_waitcnt vmcnt(12)" ::: "memory");
        } else if (tt + 1 < T) {
            if constexpr (L == 4) asm volatile("s_waitcnt vmcnt(4)" ::: "memory");
            else                  asm volatile("s_waitcnt vmcnt(6)" ::: "memory");
        } else {
            asm volatile("s_waitcnt vmcnt(0)" ::: "memory");
        }
        __builtin_amdgcn_s_barrier();

        const unsigned short* base = lds + (tt % 3) * SLOT;
        #pragma unroll
        for (int kk = 0; kk < BK / 32; kk++) {
            s16x8 a[FM], bb[2], alr[FM], blr[2];
            #pragma unroll
            for (int f = 0; f < FM; f++) a[f] = rfrag<BM>(base, wr + f * 16 + r, kk, g4);
            #pragma unroll
            for (int f = 0; f < 2; f++) bb[f] = rfrag<64>(base + A_USH, wc + f * 16 + r, kk, g4);
            if constexpr (PROD == 3) {
                #pragma unroll
                for (int f = 0; f < 2; f++) blr[f] = rfrag<64>(base + A_USH + B_USH, wc + f * 16 + r, kk, g4);
                #pragma unroll
                for (int f = 0; f < FM; f++) alr[f] = rfrag<BM>(base + A_USH + 2 * B_USH, wr + f * 16 + r, kk, g4);
            }
            __builtin_amdgcn_s_setprio(1);
            #pragma unroll
            for (int fm = 0; fm < FM; fm++)
                #pragma unroll
                for (int fn = 0; fn < 2; fn++) {
                    acc[fm][fn] = MF(a[fm], bb[fn], acc[fm][fn]);
                    if constexpr (PROD == 3) {
                        acc[fm][fn] = MF(a[fm], blr[fn], acc[fm][fn]);
                        acc[fm][fn] = MF(alr[fm], bb[fn], acc[fm][fn]);
                    }
                }
            __builtin_amdgcn_s_setprio(0);
        }
    }

    // epilogue (C/D: col = lane&15, row = 4*(lane>>4)+i — m89-verified)
    if constexpr (WMODE == 5) {
        float yacc[FM][4];
        #pragma unroll
        for (int fm = 0; fm < FM; fm++)
            #pragma unroll
            for (int i = 0; i < 4; i++) yacc[fm][i] = 0.f;
        #pragma unroll
        for (int fn = 0; fn < 2; fn++) {
            int n = col0 + wc + fn * 16 + r;
            float bn = bias[n];
            float wn = w3[n];
            #pragma unroll
            for (int fm = 0; fm < FM; fm++) {
                f32x4 v = acc[fm][fn];
                #pragma unroll
                for (int i = 0; i < 4; i++) {
                    float x = fmaxf(v[i] + bn, 0.f);
                    yacc[fm][i] += x * wn;
                }
            }
        }
        int slot = (col0 >> 6) * 2 + (w & 1);
        #pragma unroll
        for (int fm = 0; fm < FM; fm++)
            #pragma unroll
            for (int i = 0; i < 4; i++) {
                float v = yacc[fm][i];
                v += __shfl_xor(v, 1, 64);
                v += __shfl_xor(v, 2, 64);
                v += __shfl_xor(v, 4, 64);
                v += __shfl_xor(v, 8, 64);
                if ((l & 15) == 0)
                    y3p[(size_t)slot * 4096 + row0 + wr + fm * 16 + g4 * 4 + i] = v;
            }
    } else {
        #pragma unroll
        for (int fn = 0; fn < 2; fn++) {
            int n = col0 + wc + fn * 16 + r;
            float bn = bias ? bias[n] : 0.f;
            if (bias2) bn += bias2[n];
            #pragma unroll
            for (int fm = 0; fm < FM; fm++) {
                int m0 = row0 + wr + fm * 16 + g4 * 4;
                f32x4 v = acc[fm][fn];
                if constexpr (WMODE == 4) {
                    u16x4 hv;
                    #pragma unroll
                    for (int i = 0; i < 4; i++) {
                        float x = v[i] + bn;
                        if (RELU) x = fmaxf(x, 0.f);
                        hv[i] = f2bh(x);
                    }
                    *(u16x4*)(Ch + (size_t)n * ldc + m0) = hv;
                } else if constexpr (WMODE == 6) {
                    #pragma unroll
                    for (int i = 0; i < 4; i++) {
                        float x = v[i] + bn;
                        if (RELU) x = fmaxf(x, 0.f);
                        Cf[(size_t)(m0 + i) * ldc + n] = x;
                    }
                } else {  // WMODE 3: hi bf16 C[m][n]
                    #pragma unroll
                    for (int i = 0; i < 4; i++) {
                        float x = v[i] + bn;
                        if (RELU) x = fmaxf(x, 0.f);
                        Ch[(size_t)(m0 + i) * ldc + n] = f2bh(x);
                    }
                }
            }
        }
    }
}

// ---------------- fallback f32 tiled GEMM (round-1, proven) ----------------
template<int TRANSB>
__global__ __launch_bounds__(256) void gemm_f32_128(
    const float* __restrict__ A, const float* __restrict__ B, float* __restrict__ C,
    int M, int N, int K, int lda, int ldb,
    const float* __restrict__ bias, const float* __restrict__ vrow, int do_relu)
{
    constexpr int BM = 128, BN = 128, BK = 16;
    __shared__ float As[BK][BM + 4];
    __shared__ float Bs[BK][BN + 4];
    const int t = threadIdx.x;
    const int w = t >> 6, l = t & 63;
    const int cx = (w & 1) * 8 + (l & 7);
    const int cy = (w >> 1) * 8 + (l >> 3);
    const int row0 = blockIdx.y * BM;
    const int col0 = blockIdx.x * BN;

    float acc[8][8];
    #pragma unroll
    for (int i = 0; i < 8; i++)
        #pragma unroll
        for (int j = 0; j < 8; j++) acc[i][j] = 0.f;

    const int ka = t & 15;
    const int ma = t >> 4;

    for (int k0 = 0; k0 < K; k0 += BK) {
        #pragma unroll
        for (int i = 0; i < 8; i++) {
            int m = ma + i * 16;
            int gk = k0 + ka;
            float v = 0.f;
            if (gk < K) v = A[(size_t)(row0 + m) * lda + gk];
            As[ka][m] = v;
        }
        if (TRANSB) {
            #pragma unroll
            for (int i = 0; i < 8; i++) {
                int n = ma + i * 16;
                int gk = k0 + ka;
                float v = 0.f;
                if (gk < K) v = B[(size_t)(col0 + n) * ldb + gk];
                Bs[ka][n] = v;
            }
        } else {
            const int nb = t & 127;
            const int kb = t >> 7;
            #pragma unroll
            for (int i = 0; i < 8; i++) {
                int kk = kb + i * 2;
                int gk = k0 + kk;
                float v = 0.f;
                if (gk < K) v = B[(size_t)gk * ldb + col0 + nb];
                Bs[kk][nb] = v;
            }
        }
        __syncthreads();
        #pragma unroll
        for (int kk = 0; kk < BK; kk++) {
            float a[8], bb[8];
            *(float4*)&a[0]  = *(const float4*)&As[kk][cy * 8];
            *(float4*)&a[4]  = *(const float4*)&As[kk][cy * 8 + 4];
            *(float4*)&bb[0] = *(const float4*)&Bs[kk][cx * 8];
            *(float4*)&bb[4] = *(const float4*)&Bs[kk][cx * 8 + 4];
            #pragma unroll
            for (int i = 0; i < 8; i++)
                #pragma unroll
                for (int j = 0; j < 8; j++)
                    acc[i][j] = fmaf(a[i], bb[j], acc[i][j]);
        }
        __syncthreads();
    }

    #pragma unroll
    for (int i = 0; i < 8; i++) {
        int rr = row0 + cy * 8 + i;
        float vv[8];
        #pragma unroll
        for (int j = 0; j < 8; j++) {
            int c = col0 + cx * 8 + j;
            float v = acc[i][j];
            if (vrow) v += vrow[c];
            if (bias) v += bias[c];
            if (do_relu) v = fmaxf(v, 0.f);
            vv[j] = v;
        }
        float* cp = C + (size_t)rr * N + col0 + cx * 8;
        *(float4*)cp       = *(float4*)&vv[0];
        *(float4*)(cp + 4) = *(float4*)&vv[4];
    }
}

// ---------------- host launcher ----------------
extern "C" void kernel_launch(void* const* d_in, const int* in_sizes, int n_in,
                              void* d_out, int out_size, void* d_ws, size_t ws_size,
                              hipStream_t stream) {
    const float* frames     = (const float*)d_in[0];
    const float* scores     = (const float*)d_in[1];
    const float* word_embed = (const float*)d_in[2];
    const float* all_embeds = (const float*)d_in[3];
    const float* adj        = (const float*)d_in[4];
    const float* visual_W   = (const float*)d_in[5];
    const float* visual_b   = (const float*)d_in[6];
    const float* semantic_W = (const float*)d_in[7];
    const float* semantic_b = (const float*)d_in[8];
    const float* score_W    = (const float*)d_in[9];
    const float* score_b    = (const float*)d_in[10];
    const float* gc1_W      = (const float*)d_in[11];
    const float* gc1_b      = (const float*)d_in[12];
    const float* gc2_W      = (const float*)d_in[13];
    const float* gc2_b      = (const float*)d_in[14];
    const float* gc3_W      = (const float*)d_in[15];
    const float* gc3_b      = (const float*)d_in[16];
    const float* gcn512_W   = (const float*)d_in[17];
    const float* gcn512_b   = (const float*)d_in[18];
    const float* hidden_W   = (const float*)d_in[19];
    const float* hidden_b   = (const float*)d_in[20];
    const float* critic_W   = (const float*)d_in[21];
    const float* critic_b   = (const float*)d_in[22];
    const float* actor_W    = (const float*)d_in[23];
    const float* actor_b    = (const float*)d_in[24];

    float* out = (float*)d_out;

    if (ws_size >= FAST_WS) {
        char* wsb = (char*)d_ws;
        unsigned short* adj_h = (unsigned short*)(wsb + F_ADJH);
        unsigned short* emb_h = (unsigned short*)(wsb + F_EMB_H);
        unsigned short* emb_l = (unsigned short*)(wsb + F_EMB_L);
        unsigned short* sw_h  = (unsigned short*)(wsb + F_SW_H);
        unsigned short* sw_l  = (unsigned short*)(wsb + F_SW_L);
        unsigned short* w1t_h = (unsigned short*)(wsb + F_W1T_H);
        unsigned short* w1t_l = (unsigned short*)(wsb + F_W1T_L);
        unsigned short* w2t_h = (unsigned short*)(wsb + F_W2T_H);
        unsigned short* emT   = (unsigned short*)(wsb + F_EMT);
        unsigned short* p1_h  = (unsigned short*)(wsb + F_P1_H);
        unsigned short* p1_l  = (unsigned short*)(wsb + F_P1_L);
        unsigned short* h1    = (unsigned short*)(wsb + F_H1);
        unsigned short* y2t   = (unsigned short*)(wsb + F_Y2T);
        float*          p1f   = (float*)(wsb + F_P1F);   // aliases H1+Y2T (dead then)
        float*          y3p   = (float*)(wsb + F_Y3P);
        float*          vec   = (float*)(wsb + F_VEC);

        // 1. prep: all converts + vec3
        prep_kernel<<<16384 + 5120 + 640 + 512 + 1024 + 1536, 256, 0, stream>>>(
            adj, all_embeds, semantic_W, gc1_W, gc2_W,
            frames, scores, word_embed, visual_W, visual_b, semantic_b, score_W, score_b,
            adj_h, emb_h, emb_l, sw_h, sw_l, w1t_h, w1t_l, w2t_h, vec);
        // 2. vrow = s512 @ gc1_W[:512,:]
        vrow_kernel<<<8, 256, 0, stream>>>(gc1_W, vec);
        // 3. emT = relu(all_embeds @ semantic_W^T + b)^T  hi [512,4096], K=320, PROD=3
        mfma_g<64, 32, 3, 4, 1, 0><<<dim3(8, 64), 256, 0, stream>>>(
            emb_h, emb_l, sw_h, sw_l, 320, 320, 320,
            emT, nullptr, 4096, semantic_b, nullptr, nullptr, nullptr);
        // 4. P1 partials = adj @ em  f32, split-K x2  [4096,512]  (#7-shaped kernel)
        mfma_g<128, 64, 1, 6, 0, 1><<<dim3(8, 32, 2), 256, 0, stream>>>(
            adj_h, nullptr, emT, nullptr, 2048, 4096, 4096,
            nullptr, p1f, 512, nullptr, nullptr, nullptr, nullptr);
        // 4b. combine partials -> p1 hi/lo
        combine_p1_kernel<<<2048, 256, 0, stream>>>(p1f, p1_h, p1_l);
        // 5. h1 = relu(P1_hi @ W1'_hi + vrow + b1)  hi [4096,1024], K=512, PROD=1
        mfma_g<128, 64, 1, 3, 1, 0><<<dim3(16, 32), 256, 0, stream>>>(
            p1_h, nullptr, w1t_h, nullptr, 512, 512, 512,
            h1, nullptr, 1024, gc1_b, vec + OFF_VROW, nullptr, nullptr);
        // 6. y2t = (h1 @ gc2_W)^T  hi [1024,4096], K=1024
        mfma_g<128, 64, 1, 4, 0, 0><<<dim3(16, 32), 256, 0, stream>>>(
            h1, nullptr, w2t_h, nullptr, 1024, 1024, 1024,
            y2t, nullptr, 4096, nullptr, nullptr, nullptr, nullptr);
        // 7. fused: H2 = relu(adj @ Y2 + b2); y3 partials = H2 @ gc3_W  (K=4096)
        mfma_g<128, 64, 1, 5, 1, 0><<<dim3(16, 32), 256, 0, stream>>>(
            adj_h, nullptr, y2t, nullptr, 4096, 4096, 4096,
            nullptr, nullptr, 0, gc2_b, nullptr, gc3_W, y3p);
        // 8. y3 = sum of 32 partials
        y3red_kernel<<<16, 256, 0, stream>>>(y3p, vec);
        // 9-12. tail
        h3b_kernel<<<4096, 256, 0, stream>>>(adj_h, gc3_b, vec);
        gcn_kernel<<<512, 256, 0, stream>>>(gcn512_W, gcn512_b, vec);
        x_kernel<<<512, 256, 0, stream>>>(hidden_W, hidden_b, vec);
        out_kernel<<<1, 512, 0, stream>>>(vec, critic_W, critic_b, actor_W, actor_b, out);
    } else {
        // fallback f32 path (round-1, proven within 50.4 MB)
        float* ws = (float*)d_ws;
        float* em = ws + OFF_BUF0;
        float* Y1 = ws + OFF_BUF1;
        float* H1 = ws + OFF_BUF2;
        float* Y2 = ws + OFF_BUF1;
        float* H2 = ws + OFF_BUF0;

        vec3_kernel<<<1536, 256, 0, stream>>>(frames, scores, word_embed,
                                              visual_W, visual_b, semantic_W, semantic_b,
                                              score_W, score_b, ws);
        vrow_kernel<<<8, 256, 0, stream>>>(gc1_W, ws);
        gemm_f32_128<1><<<dim3(512 / 128, 4096 / 128), 256, 0, stream>>>(
            all_embeds, semantic_W, em, 4096, 512, 300, 300, 300, semantic_b, nullptr, 1);
        gemm_f32_128<0><<<dim3(1024 / 128, 4096 / 128), 256, 0, stream>>>(
            em, gc1_W + (size_t)512 * 1024, Y1, 4096, 1024, 512, 512, 1024,
            nullptr, ws + OFF_VROW, 0);
        gemm_f32_128<0><<<dim3(1024 / 128, 4096 / 128), 256, 0, stream>>>(
            adj, Y1, H1, 4096, 1024, 4096, 4096, 1024, gc1_b, nullptr, 1);
        gemm_f32_128<0><<<dim3(1024 / 128, 4096 / 128), 256, 0, stream>>>(
            H1, gc2_W, Y2, 4096, 1024, 1024, 1024, 1024, nullptr, nullptr, 0);
        gemm_f32_128<0><<<dim3(1024 / 128, 4096 / 128), 256, 0, stream>>>(
            adj, Y2, H2, 4096, 1024, 4096, 4096, 1024, gc2_b, nullptr, 1);
        y3_kernel<<<4096, 256, 0, stream>>>(H2, gc3_W, ws);
        h3_kernel<<<4096, 256, 0, stream>>>(adj, gc3_b, ws);
        gcn_kernel<<<512, 256, 0, stream>>>(gcn512_W, gcn512_b, ws);
        x_kernel<<<512, 256, 0, stream>>>(hidden_W, hidden_b, ws);
        out_kernel<<<1, 512, 0, stream>>>(ws, critic_W, critic_b, actor_W, actor_b, out);
    }

    (void)in_sizes; (void)n_in; (void)out_size;
}

// Round 8
// 191.090 us; speedup vs baseline: 1.1592x; 1.0096x over previous
//
#include <hip/hip_runtime.h>
#include <cstddef>
#include <cstdint>

typedef short  s16x8 __attribute__((ext_vector_type(8)));
typedef float  f32x4 __attribute__((ext_vector_type(4)));
typedef unsigned short u16x4 __attribute__((ext_vector_type(4)));

typedef __attribute__((address_space(1))) const void gas_void;
typedef __attribute__((address_space(3))) void las_void;

// ---------------- bf16 helpers ----------------
__device__ __forceinline__ unsigned short f2bh(float x) {
    union { float f; unsigned int u; } c; c.f = x;
    unsigned int r = c.u + 0x7fffu + ((c.u >> 16) & 1u);
    return (unsigned short)(r >> 16);
}
__device__ __forceinline__ float bh2f(unsigned short h) {
    union { unsigned int u; float f; } c; c.u = ((unsigned int)h) << 16;
    return c.f;
}
__device__ __forceinline__ f32x4 MF(s16x8 a, s16x8 b, f32x4 c) {
    return __builtin_amdgcn_mfma_f32_16x16x32_bf16(a, b, c, 0, 0, 0);
}
__device__ __forceinline__ void gload16(const unsigned short* g, unsigned short* l) {
    __builtin_amdgcn_global_load_lds((gas_void*)g, (las_void*)l, 16, 0, 0);
}

// ---------------- vec region offsets (floats) ----------------
static constexpr size_t OFF_VIS  = 0;
static constexpr size_t OFF_SEM  = 512;
static constexpr size_t OFF_GCN  = 1024;
static constexpr size_t OFF_S512 = 1536;
static constexpr size_t OFF_VROW = 2048;
static constexpr size_t OFF_X    = 3072;
static constexpr size_t OFF_Y3   = 4096;
static constexpr size_t OFF_H3   = 8192;
// fallback big buffers (floats, absolute in ws)
static constexpr size_t OFF_BUF0 = 16384;
static constexpr size_t OFF_BUF1 = OFF_BUF0 + 4194304;
static constexpr size_t OFF_BUF2 = OFF_BUF1 + 4194304;

// ---------------- fast-path ws layout (bytes) ----------------
// adj_h fixed; SCRATCH region is time-shared: early {emb,sw,w1t,w2t,emT} + p1f,
// then h1 (aliases p1f), then the WHOLE scratch becomes #7's f32 partials (p7f).
static constexpr size_t F_ADJH  = 0;                          // 33,554,432
static constexpr size_t F_SCR   = 33554432;                   // 33,554,432 scratch
static constexpr size_t F_EMB_H = F_SCR;                      // 2,621,440
static constexpr size_t F_EMB_L = F_SCR + 2621440;            // 2,621,440
static constexpr size_t F_SW_H  = F_SCR + 5242880;            // 327,680
static constexpr size_t F_SW_L  = F_SCR + 5570560;            // 327,680
static constexpr size_t F_W1T_H = F_SCR + 5898240;            // 1,048,576
static constexpr size_t F_W2T_H = F_SCR + 6946816;            // 2,097,152
static constexpr size_t F_EMT   = F_SCR + 9043968;            // 4,194,304 (ends S+13,238,272)
static constexpr size_t F_P1F   = F_SCR + 16777216;           // 16,777,216 (#4 f32 partials x2)
static constexpr size_t F_H1    = F_SCR + 16777216;           // 8,388,608 (after p1f dead)
static constexpr size_t F_P7F   = F_SCR;                      // 33,554,432 (#7 f32 partials x2)
static constexpr size_t F_P1H   = 67108864;                   // 4,194,304
static constexpr size_t F_Y2T   = 71303168;                   // 8,388,608
static constexpr size_t F_VEC   = 79691776;                   // 49,152
static constexpr size_t FAST_WS = 79740928;                   // ~76.0 MB (r2 proved >=87.7)

// ---------------- block reduction ----------------
__device__ inline float blockReduceSum256(float v) {
    #pragma unroll
    for (int o = 32; o > 0; o >>= 1) v += __shfl_down(v, o, 64);
    __shared__ float red[4];
    int w = threadIdx.x >> 6;
    if ((threadIdx.x & 63) == 0) red[w] = v;
    __syncthreads();
    if (threadIdx.x == 0) v = red[0] + red[1] + red[2] + red[3];
    return v;
}

// ---------------- vec3 body ----------------
__device__ __forceinline__ void vec3_body(int b,
                            const float* __restrict__ frames,
                            const float* __restrict__ scores,
                            const float* __restrict__ word_embed,
                            const float* __restrict__ visual_W, const float* __restrict__ visual_b,
                            const float* __restrict__ semantic_W, const float* __restrict__ semantic_b,
                            const float* __restrict__ score_W, const float* __restrict__ score_b,
                            float* __restrict__ vec) {
    const float* x; const float* W; const float* bias; float* out; int K; int row;
    if (b < 512)       { row = b;        x = frames;     W = visual_W;   bias = visual_b;   out = vec + OFF_VIS;  K = 8192; }
    else if (b < 1024) { row = b - 512;  x = word_embed; W = semantic_W; bias = semantic_b; out = vec + OFF_SEM;  K = 300;  }
    else               { row = b - 1024; x = scores;     W = score_W;    bias = score_b;    out = vec + OFF_S512; K = 1000; }
    const float* wr = W + (size_t)row * K;
    float s = 0.f;
    for (int k = threadIdx.x; k < K; k += 256) s += wr[k] * x[k];
    s = blockReduceSum256(s);
    if (threadIdx.x == 0) out[row] = fmaxf(s + bias[row], 0.f);
}

// ---------------- small kernels ----------------
__global__ void vec3_kernel(const float* __restrict__ frames,
                            const float* __restrict__ scores,
                            const float* __restrict__ word_embed,
                            const float* __restrict__ visual_W, const float* __restrict__ visual_b,
                            const float* __restrict__ semantic_W, const float* __restrict__ semantic_b,
                            const float* __restrict__ score_W, const float* __restrict__ score_b,
                            float* __restrict__ vec) {
    vec3_body(blockIdx.x, frames, scores, word_embed, visual_W, visual_b,
              semantic_W, semantic_b, score_W, score_b, vec);
}

__global__ void vrow_kernel(const float* __restrict__ gc1_W, float* __restrict__ vec) {
    __shared__ float part[128];
    const float* s512 = vec + OFF_S512;
    int jl = threadIdx.x & 127;
    int j = blockIdx.x * 128 + jl;
    int kh = threadIdx.x >> 7;
    float s = 0.f;
    #pragma unroll 4
    for (int k = kh * 256; k < kh * 256 + 256; k++)
        s += s512[k] * gc1_W[(size_t)k * 1024 + j];
    if (kh) part[jl] = s;
    __syncthreads();
    if (!kh) vec[OFF_VROW + j] = s + part[jl];
}

__global__ void y3_kernel(const float* __restrict__ H2, const float* __restrict__ gc3_W,
                          float* __restrict__ vec) {
    int i = blockIdx.x;
    const float* r = H2 + (size_t)i * 1024;
    float s = 0.f;
    for (int k = threadIdx.x; k < 1024; k += 256) s += r[k] * gc3_W[k];
    s = blockReduceSum256(s);
    if (threadIdx.x == 0) vec[OFF_Y3 + i] = s;
}

// fused: y3[i] = sum_j relu(p7f0[i,j] + p7f1[i,j] + gc2_b[j]) * gc3_W[j]
__global__ void h2y3_kernel(const float* __restrict__ p7f, const float* __restrict__ gc2_b,
                            const float* __restrict__ gc3_W, float* __restrict__ vec) {
    int i = blockIdx.x;
    const float4* r0 = (const float4*)(p7f + (size_t)i * 1024);
    const float4* r1 = (const float4*)(p7f + 4194304 + (size_t)i * 1024);
    const float4* b4 = (const float4*)gc2_b;
    const float4* w4 = (const float4*)gc3_W;
    int c = threadIdx.x;   // 256 threads x float4 = 1024
    float4 a = r0[c], b = r1[c], bb = b4[c], ww = w4[c];
    float s = fmaxf(a.x + b.x + bb.x, 0.f) * ww.x
            + fmaxf(a.y + b.y + bb.y, 0.f) * ww.y
            + fmaxf(a.z + b.z + bb.z, 0.f) * ww.z
            + fmaxf(a.w + b.w + bb.w, 0.f) * ww.w;
    s = blockReduceSum256(s);
    if (threadIdx.x == 0) vec[OFF_Y3 + i] = s;
}

// h3 from bf16 adj
__global__ void h3b_kernel(const unsigned short* __restrict__ adj_h,
                           const float* __restrict__ gc3_b, float* __restrict__ vec) {
    int i = blockIdx.x;
    const u16x4* rp = (const u16x4*)(adj_h + (size_t)i * 4096);
    const float* y3 = vec + OFF_Y3;
    float s = 0.f;
    for (int c = threadIdx.x; c < 1024; c += 256) {
        u16x4 v = rp[c];
        int k0 = c * 4;
        s += bh2f(v[0]) * y3[k0] + bh2f(v[1]) * y3[k0 + 1]
           + bh2f(v[2]) * y3[k0 + 2] + bh2f(v[3]) * y3[k0 + 3];
    }
    s = blockReduceSum256(s);
    if (threadIdx.x == 0) vec[OFF_H3 + i] = fmaxf(s + gc3_b[0], 0.f);
}

__global__ void h3_kernel(const float* __restrict__ adj, const float* __restrict__ gc3_b,
                          float* __restrict__ vec) {
    int i = blockIdx.x;
    const float* r = adj + (size_t)i * 4096;
    const float* y3 = vec + OFF_Y3;
    float s = 0.f;
    for (int k = threadIdx.x; k < 4096; k += 256) s += r[k] * y3[k];
    s = blockReduceSum256(s);
    if (threadIdx.x == 0) vec[OFF_H3 + i] = fmaxf(s + gc3_b[0], 0.f);
}

__global__ void gcn_kernel(const float* __restrict__ gcn512_W, const float* __restrict__ gcn512_b,
                           float* __restrict__ vec) {
    int j = blockIdx.x;
    const float* r = gcn512_W + (size_t)j * 4096;
    const float* h3 = vec + OFF_H3;
    float s = 0.f;
    for (int k = threadIdx.x; k < 4096; k += 256) s += r[k] * h3[k];
    s = blockReduceSum256(s);
    if (threadIdx.x == 0) vec[OFF_GCN + j] = fmaxf(s + gcn512_b[j], 0.f);
}

__global__ void x_kernel(const float* __restrict__ hidden_W, const float* __restrict__ hidden_b,
                         float* __restrict__ vec) {
    int j = blockIdx.x;
    const float* r = hidden_W + (size_t)j * 1536;
    const float* joint = vec;
    float s = 0.f;
    for (int k = threadIdx.x; k < 1536; k += 256) s += r[k] * joint[k];
    s = blockReduceSum256(s);
    if (threadIdx.x == 0) vec[OFF_X + j] = fmaxf(s + hidden_b[j], 0.f);
}

__global__ void out_kernel(const float* __restrict__ vec,
                           const float* __restrict__ critic_W, const float* __restrict__ critic_b,
                           const float* __restrict__ actor_W, const float* __restrict__ actor_b,
                           float* __restrict__ out) {
    const float* xv = vec + OFF_X;
    int w = threadIdx.x >> 6, l = threadIdx.x & 63;
    if (w >= 7) return;
    const float* row = (w == 0) ? critic_W : actor_W + (size_t)(w - 1) * 512;
    float s = 0.f;
    for (int q = l; q < 512; q += 64) s += xv[q] * row[q];
    #pragma unroll
    for (int o = 32; o > 0; o >>= 1) s += __shfl_down(s, o, 64);
    if (l == 0) out[w] = s + ((w == 0) ? critic_b[0] : actor_b[w - 1]);
}

// combine P1 split-K partials -> hi bf16 only (#5 is PROD=1)
__global__ void combine_p1_kernel(const float* __restrict__ p1f,
                                  unsigned short* __restrict__ hi) {
    size_t i = (size_t)blockIdx.x * 256 + threadIdx.x;    // float4 index over 524288
    float4 a = ((const float4*)p1f)[i];
    float4 b = ((const float4*)(p1f + 2097152))[i];
    u16x4 hv;
    hv[0] = f2bh(a.x + b.x);
    hv[1] = f2bh(a.y + b.y);
    hv[2] = f2bh(a.z + b.z);
    hv[3] = f2bh(a.w + b.w);
    *(u16x4*)(hi + i * 4) = hv;
}

// ---------------- fused prep kernel: all converts + vec3 ----------------
__global__ void prep_kernel(const float* __restrict__ adj,
                            const float* __restrict__ all_embeds,
                            const float* __restrict__ semantic_W,
                            const float* __restrict__ gc1_W,
                            const float* __restrict__ gc2_W,
                            const float* __restrict__ frames,
                            const float* __restrict__ scores,
                            const float* __restrict__ word_embed,
                            const float* __restrict__ visual_W, const float* __restrict__ visual_b,
                            const float* __restrict__ semantic_b,
                            const float* __restrict__ score_W, const float* __restrict__ score_b,
                            unsigned short* __restrict__ adj_h,
                            unsigned short* __restrict__ emb_h, unsigned short* __restrict__ emb_l,
                            unsigned short* __restrict__ sw_h, unsigned short* __restrict__ sw_l,
                            unsigned short* __restrict__ w1t_h,
                            unsigned short* __restrict__ w2t_h,
                            float* __restrict__ vec) {
    __shared__ float tile[32][33];
    const int b = blockIdx.x, t = threadIdx.x;
    if (b < 16384) {
        size_t i = (size_t)b * 256 + t;
        float4 v = ((const float4*)adj)[i];
        u16x4 h; h[0] = f2bh(v.x); h[1] = f2bh(v.y); h[2] = f2bh(v.z); h[3] = f2bh(v.w);
        *(u16x4*)(adj_h + i * 4) = h;
    } else if (b < 16384 + 5120) {
        size_t i = (size_t)(b - 16384) * 256 + t;   // over 4096*320
        int r = (int)(i / 320), c = (int)(i % 320);
        float v = (c < 300) ? all_embeds[(size_t)r * 300 + c] : 0.f;
        unsigned short h = f2bh(v);
        emb_h[i] = h; emb_l[i] = f2bh(v - bh2f(h));
    } else if (b < 16384 + 5120 + 640) {
        size_t i = (size_t)(b - 16384 - 5120) * 256 + t;   // over 512*320
        int r = (int)(i / 320), c = (int)(i % 320);
        float v = (c < 300) ? semantic_W[(size_t)r * 300 + c] : 0.f;
        unsigned short h = f2bh(v);
        sw_h[i] = h; sw_l[i] = f2bh(v - bh2f(h));
    } else if (b < 16384 + 5120 + 640 + 512) {
        // w1T: src = gc1_W[512:,:] f32 [K=512, N=1024] -> [N,K] hi only
        int l2 = b - 16384 - 5120 - 640;
        const float* src = gc1_W + (size_t)512 * 1024;
        int kb = (l2 & 15) * 32, nb = (l2 >> 4) * 32;
        int tx = t & 31, ty = t >> 5;
        #pragma unroll
        for (int i = 0; i < 32; i += 8)
            tile[ty + i][tx] = src[(size_t)(kb + ty + i) * 1024 + nb + tx];
        __syncthreads();
        #pragma unroll
        for (int i = 0; i < 32; i += 8) {
            int n = nb + ty + i, k = kb + tx;
            w1t_h[(size_t)n * 512 + k] = f2bh(tile[tx][ty + i]);
        }
    } else if (b < 16384 + 5120 + 640 + 512 + 1024) {
        // w2T: gc2_W f32 [1024,1024] -> [N,K] hi
        int l2 = b - 16384 - 5120 - 640 - 512;
        int kb = (l2 & 31) * 32, nb = (l2 >> 5) * 32;
        int tx = t & 31, ty = t >> 5;
        #pragma unroll
        for (int i = 0; i < 32; i += 8)
            tile[ty + i][tx] = gc2_W[(size_t)(kb + ty + i) * 1024 + nb + tx];
        __syncthreads();
        #pragma unroll
        for (int i = 0; i < 32; i += 8) {
            int n = nb + ty + i, k = kb + tx;
            w2t_h[(size_t)n * 1024 + k] = f2bh(tile[tx][ty + i]);
        }
    } else {
        vec3_body(b - (16384 + 5120 + 640 + 512 + 1024), frames, scores, word_embed,
                  visual_W, visual_b, semantic_W, semantic_b, score_W, score_b, vec);
    }
}

// ---------------- staging helpers ----------------
template<int NCHP, int NJ>
__device__ __forceinline__ void stg_mat(const unsigned short* __restrict__ src, int ld, int r0,
                                        int k0, unsigned short* dst, int t) {
    #pragma unroll
    for (int j = 0; j < NJ; j++) {
        int c = j * 256 + t;
        int p = c / NCHP;
        int idx = c % NCHP;
        int row = idx >> 2;
        int gg = (idx & 3) ^ ((row >> 1) & 3);
        gload16(src + (size_t)(r0 + row) * ld + (k0 + p * 32 + gg * 8),
                dst + (size_t)(j * 256 + (t & ~63)) * 8);
    }
}

template<int ROWS>
__device__ __forceinline__ s16x8 rfrag(const unsigned short* rb, int row, int p, int g4) {
    int byte = (p * ROWS + row) * 64 + ((g4 ^ ((row >> 1) & 3)) << 4);
    return *(const s16x8*)((const char*)rb + byte);
}

// ---------------- 4-wave MFMA GEMM (round-4 proven structure) ----------------
// C[M,N] = A[M,K] @ B^T ; tile BM x 64, wave (BM/2) x 32.
// PROD: 1 = Ah*Bh ; 3 = Ah*Bh + Ah*Bl + Al*Bh
// WMODE: 3 hi C[m][n]; 4 hi C^T[n][m] (ldc=M); 6 f32 C[m][n]
// SPLITK: blockIdx.z selects K-chunk; Ah/Bh advance z*K; Cf advances z*M*N.
template<int BM, int BK, int PROD, int WMODE, int RELU, int SPLITK>
__global__ __launch_bounds__(256) void mfma_g(
    const unsigned short* __restrict__ Ah, const unsigned short* __restrict__ Al,
    const unsigned short* __restrict__ Bh, const unsigned short* __restrict__ Bl,
    int K, int lda, int ldb,
    unsigned short* __restrict__ Ch, float* __restrict__ Cf, int ldc,
    const float* __restrict__ bias, const float* __restrict__ bias2)
{
    constexpr int A_USH = BM * BK;
    constexpr int B_USH = 64 * BK;
    constexpr int A_CH  = A_USH / 8;
    constexpr int B_CH  = B_USH / 8;
    constexpr int SLOT  = (PROD == 3) ? 2 * (A_USH + B_USH) : (A_USH + B_USH);
    constexpr int L     = ((A_CH + B_CH) / 256) * ((PROD == 3) ? 2 : 1);
    constexpr int FM    = BM / 32;
    __shared__ unsigned short lds[3 * SLOT];

    const int t = threadIdx.x;
    const int w = t >> 6, l = t & 63;
    const int r = l & 15, g4 = l >> 4;
    const int wr = (w >> 1) * (BM / 2);
    const int wc = (w & 1) * 32;

    const int gx = gridDim.x;
    const int nwg = gx * gridDim.y;
    int flat = blockIdx.y * gx + blockIdx.x;
    int swz = (flat & 7) * (nwg >> 3) + (flat >> 3);
    const int col0 = (swz % gx) * 64;
    const int row0 = (swz / gx) * BM;

    if constexpr (SPLITK) {
        int z = blockIdx.z;
        Ah += (size_t)z * K;
        Bh += (size_t)z * K;
        Cf += (size_t)z * (size_t)nwg * (BM * 64);
    }

    f32x4 acc[FM][2];
    #pragma unroll
    for (int a = 0; a < FM; a++)
        #pragma unroll
        for (int b = 0; b < 2; b++) acc[a][b] = (f32x4){0.f, 0.f, 0.f, 0.f};

    auto stage = [&](int slot, int k0) {
        unsigned short* base = lds + slot * SLOT;
        stg_mat<BM * 4, A_CH / 256>(Ah, lda, row0, k0, base, t);
        stg_mat<256,    B_CH / 256>(Bh, ldb, col0, k0, base + A_USH, t);
        if constexpr (PROD == 3) {
            stg_mat<256,    B_CH / 256>(Bl, ldb, col0, k0, base + A_USH + B_USH, t);
            stg_mat<BM * 4, A_CH / 256>(Al, lda, row0, k0, base + A_USH + 2 * B_USH, t);
        }
    };

    const int T = K / BK;
    stage(0, 0);
    stage(1, BK);

    for (int tt = 0; tt < T; ++tt) {
        __builtin_amdgcn_s_barrier();
        if (tt + 2 < T) {
            stage((tt + 2) % 3, (tt + 2) * BK);
            if constexpr (L == 4) asm volatile("s_waitcnt vmcnt(8)" ::: "memory");
            else                  asm volatile("s_waitcnt vmcnt(12)" ::: "memory");
        } else if (tt + 1 < T) {
            if constexpr (L == 4) asm volatile("s_waitcnt vmcnt(4)" ::: "memory");
            else                  asm volatile("s_waitcnt vmcnt(6)" ::: "memory");
        } else {
            asm volatile("s_waitcnt vmcnt(0)" ::: "memory");
        }
        __builtin_amdgcn_s_barrier();

        const unsigned short* base = lds + (tt % 3) * SLOT;
        #pragma unroll
        for (int kk = 0; kk < BK / 32; kk++) {
            s16x8 a[FM], bb[2], alr[FM], blr[2];
            #pragma unroll
            for (int f = 0; f < FM; f++) a[f] = rfrag<BM>(base, wr + f * 16 + r, kk, g4);
            #pragma unroll
            for (int f = 0; f < 2; f++) bb[f] = rfrag<64>(base + A_USH, wc + f * 16 + r, kk, g4);
            if constexpr (PROD == 3) {
                #pragma unroll
                for (int f = 0; f < 2; f++) blr[f] = rfrag<64>(base + A_USH + B_USH, wc + f * 16 + r, kk, g4);
                #pragma unroll
                for (int f = 0; f < FM; f++) alr[f] = rfrag<BM>(base + A_USH + 2 * B_USH, wr + f * 16 + r, kk, g4);
            }
            __builtin_amdgcn_s_setprio(1);
            #pragma unroll
            for (int fm = 0; fm < FM; fm++)
                #pragma unroll
                for (int fn = 0; fn < 2; fn++) {
                    acc[fm][fn] = MF(a[fm], bb[fn], acc[fm][fn]);
                    if constexpr (PROD == 3) {
                        acc[fm][fn] = MF(a[fm], blr[fn], acc[fm][fn]);
                        acc[fm][fn] = MF(alr[fm], bb[fn], acc[fm][fn]);
                    }
                }
            __builtin_amdgcn_s_setprio(0);
        }
    }

    // epilogue (C/D: col = lane&15, row = 4*(lane>>4)+i — m89-verified)
    #pragma unroll
    for (int fn = 0; fn < 2; fn++) {
        int n = col0 + wc + fn * 16 + r;
        float bn = bias ? bias[n] : 0.f;
        if (bias2) bn += bias2[n];
        #pragma unroll
        for (int fm = 0; fm < FM; fm++) {
            int m0 = row0 + wr + fm * 16 + g4 * 4;
            f32x4 v = acc[fm][fn];
            if constexpr (WMODE == 4) {
                u16x4 hv;
                #pragma unroll
                for (int i = 0; i < 4; i++) {
                    float x = v[i] + bn;
                    if (RELU) x = fmaxf(x, 0.f);
                    hv[i] = f2bh(x);
                }
                *(u16x4*)(Ch + (size_t)n * ldc + m0) = hv;
            } else if constexpr (WMODE == 6) {
                #pragma unroll
                for (int i = 0; i < 4; i++) {
                    float x = v[i] + bn;
                    if (RELU) x = fmaxf(x, 0.f);
                    Cf[(size_t)(m0 + i) * ldc + n] = x;
                }
            } else {  // WMODE 3: hi bf16 C[m][n]
                #pragma unroll
                for (int i = 0; i < 4; i++) {
                    float x = v[i] + bn;
                    if (RELU) x = fmaxf(x, 0.f);
                    Ch[(size_t)(m0 + i) * ldc + n] = f2bh(x);
                }
            }
        }
    }
}

// ---------------- 4-wave SQUARE-tile GEMM: 128x128, wave 64x64, BK=32, ring-3, split-K ----
// C f32 partials: Cf[z*4096*1024 + m*ldc + n] = sum over this z's K-chunk of A@B^T.
// LDS slot 16 KB, ring-3 = 48 KB -> grid 512 blocks = 2 blocks/CU = 8 waves/CU (2/SIMD).
__global__ __launch_bounds__(256) void mfma_sq(
    const unsigned short* __restrict__ Ah,
    const unsigned short* __restrict__ Bh,
    int Kc, int lda, int ldb,
    float* __restrict__ Cf, int ldc)
{
    constexpr int A_USH = 128 * 32;           // 4096 ush
    constexpr int SLOT  = 2 * A_USH;          // 8192 ush = 16 KB
    __shared__ unsigned short lds[3 * SLOT];

    const int t = threadIdx.x;
    const int w = t >> 6, l = t & 63;
    const int r = l & 15, g4 = l >> 4;
    const int wr = (w >> 1) * 64, wc = (w & 1) * 64;

    const int gx = gridDim.x;
    const int nwg = gx * gridDim.y;
    int flat = blockIdx.y * gx + blockIdx.x;
    int swz = (flat & 7) * (nwg >> 3) + (flat >> 3);
    const int col0 = (swz % gx) * 128;
    const int row0 = (swz / gx) * 128;

    const int z = blockIdx.z;
    Ah += (size_t)z * Kc;
    Bh += (size_t)z * Kc;
    Cf += (size_t)z * 4194304;

    f32x4 acc[4][4];
    #pragma unroll
    for (int a = 0; a < 4; a++)
        #pragma unroll
        for (int b = 0; b < 4; b++) acc[a][b] = (f32x4){0.f, 0.f, 0.f, 0.f};

    auto stage = [&](int slot, int k0) {
        unsigned short* base = lds + slot * SLOT;
        stg_mat<512, 2>(Ah, lda, row0, k0, base, t);
        stg_mat<512, 2>(Bh, ldb, col0, k0, base + A_USH, t);
    };

    const int T = Kc >> 5;
    stage(0, 0);
    stage(1, 32);

    for (int tt = 0; tt < T; ++tt) {
        __builtin_amdgcn_s_barrier();
        if (tt + 2 < T) {
            stage((tt + 2) % 3, (tt + 2) * 32);
            asm volatile("s_waitcnt vmcnt(8)" ::: "memory");
        } else if (tt + 1 < T) {
            asm volatile("s_waitcnt vmcnt(4)" ::: "memory");
        } else {
            asm volatile("s_waitcnt vmcnt(0)" ::: "memory");
        }
        __builtin_amdgcn_s_barrier();

        const unsigned short* base = lds + (tt % 3) * SLOT;
        s16x8 a[4], bb[4];
        #pragma unroll
        for (int f = 0; f < 4; f++) a[f] = rfrag<128>(base, wr + f * 16 + r, 0, g4);
        #pragma unroll
        for (int f = 0; f < 4; f++) bb[f] = rfrag<128>(base + A_USH, wc + f * 16 + r, 0, g4);
        __builtin_amdgcn_s_setprio(1);
        #pragma unroll
        for (int fm = 0; fm < 4; fm++)
            #pragma unroll
            for (int fn = 0; fn < 4; fn++)
                acc[fm][fn] = MF(a[fm], bb[fn], acc[fm][fn]);
        __builtin_amdgcn_s_setprio(0);
    }

    // epilogue: f32 partials (C/D: col = lane&15, row = 4*(lane>>4)+i)
    #pragma unroll
    for (int fn = 0; fn < 4; fn++) {
        int n = col0 + wc + fn * 16 + r;
        #pragma unroll
        for (int fm = 0; fm < 4; fm++) {
            int m0 = row0 + wr + fm * 16 + g4 * 4;
            f32x4 v = acc[fm][fn];
            #pragma unroll
            for (int i = 0; i < 4; i++)
                Cf[(size_t)(m0 + i) * ldc + n] = v[i];
        }
    }
}

// ---------------- fallback f32 tiled GEMM (round-1, proven) ----------------
template<int TRANSB>
__global__ __launch_bounds__(256) void gemm_f32_128(
    const float* __restrict__ A, const float* __restrict__ B, float* __restrict__ C,
    int M, int N, int K, int lda, int ldb,
    const float* __restrict__ bias, const float* __restrict__ vrow, int do_relu)
{
    constexpr int BM = 128, BN = 128, BK = 16;
    __shared__ float As[BK][BM + 4];
    __shared__ float Bs[BK][BN + 4];
    const int t = threadIdx.x;
    const int w = t >> 6, l = t & 63;
    const int cx = (w & 1) * 8 + (l & 7);
    const int cy = (w >> 1) * 8 + (l >> 3);
    const int row0 = blockIdx.y * BM;
    const int col0 = blockIdx.x * BN;

    float acc[8][8];
    #pragma unroll
    for (int i = 0; i < 8; i++)
        #pragma unroll
        for (int j = 0; j < 8; j++) acc[i][j] = 0.f;

    const int ka = t & 15;
    const int ma = t >> 4;

    for (int k0 = 0; k0 < K; k0 += BK) {
        #pragma unroll
        for (int i = 0; i < 8; i++) {
            int m = ma + i * 16;
            int gk = k0 + ka;
            float v = 0.f;
            if (gk < K) v = A[(size_t)(row0 + m) * lda + gk];
            As[ka][m] = v;
        }
        if (TRANSB) {
            #pragma unroll
            for (int i = 0; i < 8; i++) {
                int n = ma + i * 16;
                int gk = k0 + ka;
                float v = 0.f;
                if (gk < K) v = B[(size_t)(col0 + n) * ldb + gk];
                Bs[ka][n] = v;
            }
        } else {
            const int nb = t & 127;
            const int kb = t >> 7;
            #pragma unroll
            for (int i = 0; i < 8; i++) {
                int kk = kb + i * 2;
                int gk = k0 + kk;
                float v = 0.f;
                if (gk < K) v = B[(size_t)gk * ldb + col0 + nb];
                Bs[kk][nb] = v;
            }
        }
        __syncthreads();
        #pragma unroll
        for (int kk = 0; kk < BK; kk++) {
            float a[8], bb[8];
            *(float4*)&a[0]  = *(const float4*)&As[kk][cy * 8];
            *(float4*)&a[4]  = *(const float4*)&As[kk][cy * 8 + 4];
            *(float4*)&bb[0] = *(const float4*)&Bs[kk][cx * 8];
            *(float4*)&bb[4] = *(const float4*)&Bs[kk][cx * 8 + 4];
            #pragma unroll
            for (int i = 0; i < 8; i++)
                #pragma unroll
                for (int j = 0; j < 8; j++)
                    acc[i][j] = fmaf(a[i], bb[j], acc[i][j]);
        }
        __syncthreads();
    }

    #pragma unroll
    for (int i = 0; i < 8; i++) {
        int rr = row0 + cy * 8 + i;
        float vv[8];
        #pragma unroll
        for (int j = 0; j < 8; j++) {
            int c = col0 + cx * 8 + j;
            float v = acc[i][j];
            if (vrow) v += vrow[c];
            if (bias) v += bias[c];
            if (do_relu) v = fmaxf(v, 0.f);
            vv[j] = v;
        }
        float* cp = C + (size_t)rr * N + col0 + cx * 8;
        *(float4*)cp       = *(float4*)&vv[0];
        *(float4*)(cp + 4) = *(float4*)&vv[4];
    }
}

// ---------------- host launcher ----------------
extern "C" void kernel_launch(void* const* d_in, const int* in_sizes, int n_in,
                              void* d_out, int out_size, void* d_ws, size_t ws_size,
                              hipStream_t stream) {
    const float* frames     = (const float*)d_in[0];
    const float* scores     = (const float*)d_in[1];
    const float* word_embed = (const float*)d_in[2];
    const float* all_embeds = (const float*)d_in[3];
    const float* adj        = (const float*)d_in[4];
    const float* visual_W   = (const float*)d_in[5];
    const float* visual_b   = (const float*)d_in[6];
    const float* semantic_W = (const float*)d_in[7];
    const float* semantic_b = (const float*)d_in[8];
    const float* score_W    = (const float*)d_in[9];
    const float* score_b    = (const float*)d_in[10];
    const float* gc1_W      = (const float*)d_in[11];
    const float* gc1_b      = (const float*)d_in[12];
    const float* gc2_W      = (const float*)d_in[13];
    const float* gc2_b      = (const float*)d_in[14];
    const float* gc3_W      = (const float*)d_in[15];
    const float* gc3_b      = (const float*)d_in[16];
    const float* gcn512_W   = (const float*)d_in[17];
    const float* gcn512_b   = (const float*)d_in[18];
    const float* hidden_W   = (const float*)d_in[19];
    const float* hidden_b   = (const float*)d_in[20];
    const float* critic_W   = (const float*)d_in[21];
    const float* critic_b   = (const float*)d_in[22];
    const float* actor_W    = (const float*)d_in[23];
    const float* actor_b    = (const float*)d_in[24];

    float* out = (float*)d_out;

    if (ws_size >= FAST_WS) {
        char* wsb = (char*)d_ws;
        unsigned short* adj_h = (unsigned short*)(wsb + F_ADJH);
        unsigned short* emb_h = (unsigned short*)(wsb + F_EMB_H);
        unsigned short* emb_l = (unsigned short*)(wsb + F_EMB_L);
        unsigned short* sw_h  = (unsigned short*)(wsb + F_SW_H);
        unsigned short* sw_l  = (unsigned short*)(wsb + F_SW_L);
        unsigned short* w1t_h = (unsigned short*)(wsb + F_W1T_H);
        unsigned short* w2t_h = (unsigned short*)(wsb + F_W2T_H);
        unsigned short* emT   = (unsigned short*)(wsb + F_EMT);
        float*          p1f   = (float*)(wsb + F_P1F);
        unsigned short* p1_h  = (unsigned short*)(wsb + F_P1H);
        unsigned short* h1    = (unsigned short*)(wsb + F_H1);
        unsigned short* y2t   = (unsigned short*)(wsb + F_Y2T);
        float*          p7f   = (float*)(wsb + F_P7F);
        float*          vec   = (float*)(wsb + F_VEC);

        // 1. prep: all converts + vec3
        prep_kernel<<<16384 + 5120 + 640 + 512 + 1024 + 1536, 256, 0, stream>>>(
            adj, all_embeds, semantic_W, gc1_W, gc2_W,
            frames, scores, word_embed, visual_W, visual_b, semantic_b, score_W, score_b,
            adj_h, emb_h, emb_l, sw_h, sw_l, w1t_h, w2t_h, vec);
        // 2. vrow = s512 @ gc1_W[:512,:]
        vrow_kernel<<<8, 256, 0, stream>>>(gc1_W, vec);
        // 3. emT = relu(all_embeds @ semantic_W^T + b)^T  hi [512,4096], K=320, PROD=3
        mfma_g<64, 32, 3, 4, 1, 0><<<dim3(8, 64), 256, 0, stream>>>(
            emb_h, emb_l, sw_h, sw_l, 320, 320, 320,
            emT, nullptr, 4096, semantic_b, nullptr);
        // 4. P1 partials = adj @ em  f32, split-K x2  [4096,512]
        mfma_g<128, 64, 1, 6, 0, 1><<<dim3(8, 32, 2), 256, 0, stream>>>(
            adj_h, nullptr, emT, nullptr, 2048, 4096, 4096,
            nullptr, p1f, 512, nullptr, nullptr);
        // 4b. combine partials -> p1 hi
        combine_p1_kernel<<<2048, 256, 0, stream>>>(p1f, p1_h);
        // 5. h1 = relu(P1_hi @ W1'_hi + vrow + b1)  hi [4096,1024], K=512, PROD=1
        mfma_g<128, 64, 1, 3, 1, 0><<<dim3(16, 32), 256, 0, stream>>>(
            p1_h, nullptr, w1t_h, nullptr, 512, 512, 512,
            h1, nullptr, 1024, gc1_b, vec + OFF_VROW);
        // 6. y2t = (h1 @ gc2_W)^T  hi [1024,4096], K=1024
        mfma_g<128, 64, 1, 4, 0, 0><<<dim3(16, 32), 256, 0, stream>>>(
            h1, nullptr, w2t_h, nullptr, 1024, 1024, 1024,
            y2t, nullptr, 4096, nullptr, nullptr);
        // 7. p7f partials = adj @ Y2  f32, square tiles, split-K x2  [4096,1024]
        mfma_sq<<<dim3(8, 32, 2), 256, 0, stream>>>(
            adj_h, y2t, 2048, 4096, 4096, p7f, 1024);
        // 7b. y3[i] = sum_j relu(p7f0+p7f1+b2)[i,j] * gc3_W[j]
        h2y3_kernel<<<4096, 256, 0, stream>>>(p7f, gc2_b, gc3_W, vec);
        // 8-11. tail
        h3b_kernel<<<4096, 256, 0, stream>>>(adj_h, gc3_b, vec);
        gcn_kernel<<<512, 256, 0, stream>>>(gcn512_W, gcn512_b, vec);
        x_kernel<<<512, 256, 0, stream>>>(hidden_W, hidden_b, vec);
        out_kernel<<<1, 512, 0, stream>>>(vec, critic_W, critic_b, actor_W, actor_b, out);
    } else {
        // fallback f32 path (round-1, proven within 50.4 MB)
        float* ws = (float*)d_ws;
        float* em = ws + OFF_BUF0;
        float* Y1 = ws + OFF_BUF1;
        float* H1 = ws + OFF_BUF2;
        float* Y2 = ws + OFF_BUF1;
        float* H2 = ws + OFF_BUF0;

        vec3_kernel<<<1536, 256, 0, stream>>>(frames, scores, word_embed,
                                              visual_W, visual_b, semantic_W, semantic_b,
                                              score_W, score_b, ws);
        vrow_kernel<<<8, 256, 0, stream>>>(gc1_W, ws);
        gemm_f32_128<1><<<dim3(512 / 128, 4096 / 128), 256, 0, stream>>>(
            all_embeds, semantic_W, em, 4096, 512, 300, 300, 300, semantic_b, nullptr, 1);
        gemm_f32_128<0><<<dim3(1024 / 128, 4096 / 128), 256, 0, stream>>>(
            em, gc1_W + (size_t)512 * 1024, Y1, 4096, 1024, 512, 512, 1024,
            nullptr, ws + OFF_VROW, 0);
        gemm_f32_128<0><<<dim3(1024 / 128, 4096 / 128), 256, 0, stream>>>(
            adj, Y1, H1, 4096, 1024, 4096, 4096, 1024, gc1_b, nullptr, 1);
        gemm_f32_128<0><<<dim3(1024 / 128, 4096 / 128), 256, 0, stream>>>(
            H1, gc2_W, Y2, 4096, 1024, 1024, 1024, 1024, nullptr, nullptr, 0);
        gemm_f32_128<0><<<dim3(1024 / 128, 4096 / 128), 256, 0, stream>>>(
            adj, Y2, H2, 4096, 1024, 4096, 4096, 1024, gc2_b, nullptr, 1);
        y3_kernel<<<4096, 256, 0, stream>>>(H2, gc3_W, ws);
        h3_kernel<<<4096, 256, 0, stream>>>(adj, gc3_b, ws);
        gcn_kernel<<<512, 256, 0, stream>>>(gcn512_W, gcn512_b, ws);
        x_kernel<<<512, 256, 0, stream>>>(hidden_W, hidden_b, ws);
        out_kernel<<<1, 512, 0, stream>>>(ws, critic_W, critic_b, actor_W, actor_b, out);
    }

    (void)in_sizes; (void)n_in; (void)out_size;
}

// Round 9
// 184.767 us; speedup vs baseline: 1.1989x; 1.0342x over previous
//
#include <hip/hip_runtime.h>
#include <cstddef>
#include <cstdint>

typedef short  s16x8 __attribute__((ext_vector_type(8)));
typedef float  f32x4 __attribute__((ext_vector_type(4)));
typedef unsigned short u16x4 __attribute__((ext_vector_type(4)));

typedef __attribute__((address_space(1))) const void gas_void;
typedef __attribute__((address_space(3))) void las_void;

// ---------------- bf16 helpers ----------------
__device__ __forceinline__ unsigned short f2bh(float x) {
    union { float f; unsigned int u; } c; c.f = x;
    unsigned int r = c.u + 0x7fffu + ((c.u >> 16) & 1u);
    return (unsigned short)(r >> 16);
}
__device__ __forceinline__ float bh2f(unsigned short h) {
    union { unsigned int u; float f; } c; c.u = ((unsigned int)h) << 16;
    return c.f;
}
__device__ __forceinline__ f32x4 MF(s16x8 a, s16x8 b, f32x4 c) {
    return __builtin_amdgcn_mfma_f32_16x16x32_bf16(a, b, c, 0, 0, 0);
}
__device__ __forceinline__ void gload16(const unsigned short* g, unsigned short* l) {
    __builtin_amdgcn_global_load_lds((gas_void*)g, (las_void*)l, 16, 0, 0);
}

// ---------------- vec region offsets (floats) ----------------
static constexpr size_t OFF_VIS  = 0;
static constexpr size_t OFF_SEM  = 512;
static constexpr size_t OFF_GCN  = 1024;
static constexpr size_t OFF_S512 = 1536;
static constexpr size_t OFF_VROW = 2048;
static constexpr size_t OFF_X    = 3072;
static constexpr size_t OFF_Y3   = 4096;
static constexpr size_t OFF_H3   = 8192;
// fallback big buffers (floats, absolute in ws)
static constexpr size_t OFF_BUF0 = 16384;
static constexpr size_t OFF_BUF1 = OFF_BUF0 + 4194304;
static constexpr size_t OFF_BUF2 = OFF_BUF1 + 4194304;

// ---------------- fast-path ws layout (bytes) ----------------
static constexpr size_t F_ADJH  = 0;                          // 33,554,432
static constexpr size_t F_SCR   = 33554432;                   // 33,554,432 scratch
static constexpr size_t F_EMB_H = F_SCR;                      // 2,621,440
static constexpr size_t F_EMB_L = F_SCR + 2621440;            // 2,621,440
static constexpr size_t F_SW_H  = F_SCR + 5242880;            // 327,680
static constexpr size_t F_SW_L  = F_SCR + 5570560;            // 327,680
static constexpr size_t F_W1T_H = F_SCR + 5898240;            // 1,048,576
static constexpr size_t F_W2T_H = F_SCR + 6946816;            // 2,097,152
static constexpr size_t F_EMT   = F_SCR + 9043968;            // 4,194,304
static constexpr size_t F_P1F   = F_SCR + 16777216;           // 16,777,216 (#4 f32 partials x2)
static constexpr size_t F_H1    = F_SCR + 16777216;           // 8,388,608 (after p1f dead)
static constexpr size_t F_P7F   = F_SCR;                      // 33,554,432 (#7 f32 partials x2)
static constexpr size_t F_P1H   = 67108864;                   // 4,194,304
static constexpr size_t F_Y2T   = 71303168;                   // 8,388,608
static constexpr size_t F_VEC   = 79691776;                   // 49,152
static constexpr size_t FAST_WS = 79740928;                   // ~76.0 MB

// ---------------- block reduction ----------------
__device__ inline float blockReduceSum256(float v) {
    #pragma unroll
    for (int o = 32; o > 0; o >>= 1) v += __shfl_down(v, o, 64);
    __shared__ float red[4];
    int w = threadIdx.x >> 6;
    if ((threadIdx.x & 63) == 0) red[w] = v;
    __syncthreads();
    if (threadIdx.x == 0) v = red[0] + red[1] + red[2] + red[3];
    return v;
}

// ---------------- vec3 body (visual branch float4-vectorized) ----------------
__device__ __forceinline__ void vec3_body(int b,
                            const float* __restrict__ frames,
                            const float* __restrict__ scores,
                            const float* __restrict__ word_embed,
                            const float* __restrict__ visual_W, const float* __restrict__ visual_b,
                            const float* __restrict__ semantic_W, const float* __restrict__ semantic_b,
                            const float* __restrict__ score_W, const float* __restrict__ score_b,
                            float* __restrict__ vec) {
    if (b < 512) {
        int row = b;
        const float4* w4 = (const float4*)(visual_W + (size_t)row * 8192);
        const float4* x4 = (const float4*)frames;
        float s = 0.f;
        #pragma unroll
        for (int c0 = 0; c0 < 2048; c0 += 256) {
            int c = c0 + threadIdx.x;
            float4 wv = w4[c], xv = x4[c];
            s += wv.x * xv.x + wv.y * xv.y + wv.z * xv.z + wv.w * xv.w;
        }
        s = blockReduceSum256(s);
        if (threadIdx.x == 0) (vec + OFF_VIS)[row] = fmaxf(s + visual_b[row], 0.f);
        return;
    }
    const float* x; const float* W; const float* bias; float* out; int K; int row;
    if (b < 1024) { row = b - 512;  x = word_embed; W = semantic_W; bias = semantic_b; out = vec + OFF_SEM;  K = 300;  }
    else          { row = b - 1024; x = scores;     W = score_W;    bias = score_b;    out = vec + OFF_S512; K = 1000; }
    const float* wr = W + (size_t)row * K;
    float s = 0.f;
    for (int k = threadIdx.x; k < K; k += 256) s += wr[k] * x[k];
    s = blockReduceSum256(s);
    if (threadIdx.x == 0) out[row] = fmaxf(s + bias[row], 0.f);
}

// ---------------- small kernels ----------------
__global__ void vec3_kernel(const float* __restrict__ frames,
                            const float* __restrict__ scores,
                            const float* __restrict__ word_embed,
                            const float* __restrict__ visual_W, const float* __restrict__ visual_b,
                            const float* __restrict__ semantic_W, const float* __restrict__ semantic_b,
                            const float* __restrict__ score_W, const float* __restrict__ score_b,
                            float* __restrict__ vec) {
    vec3_body(blockIdx.x, frames, scores, word_embed, visual_W, visual_b,
              semantic_W, semantic_b, score_W, score_b, vec);
}

__global__ void vrow_kernel(const float* __restrict__ gc1_W, float* __restrict__ vec) {
    __shared__ float part[128];
    const float* s512 = vec + OFF_S512;
    int jl = threadIdx.x & 127;
    int j = blockIdx.x * 128 + jl;
    int kh = threadIdx.x >> 7;
    float s = 0.f;
    #pragma unroll 4
    for (int k = kh * 256; k < kh * 256 + 256; k++)
        s += s512[k] * gc1_W[(size_t)k * 1024 + j];
    if (kh) part[jl] = s;
    __syncthreads();
    if (!kh) vec[OFF_VROW + j] = s + part[jl];
}

__global__ void y3_kernel(const float* __restrict__ H2, const float* __restrict__ gc3_W,
                          float* __restrict__ vec) {
    int i = blockIdx.x;
    const float* r = H2 + (size_t)i * 1024;
    float s = 0.f;
    for (int k = threadIdx.x; k < 1024; k += 256) s += r[k] * gc3_W[k];
    s = blockReduceSum256(s);
    if (threadIdx.x == 0) vec[OFF_Y3 + i] = s;
}

// fused: y3[i] = sum_j relu(p7f0[i,j] + p7f1[i,j] + gc2_b[j]) * gc3_W[j]
__global__ void h2y3_kernel(const float* __restrict__ p7f, const float* __restrict__ gc2_b,
                            const float* __restrict__ gc3_W, float* __restrict__ vec) {
    int i = blockIdx.x;
    const float4* r0 = (const float4*)(p7f + (size_t)i * 1024);
    const float4* r1 = (const float4*)(p7f + 4194304 + (size_t)i * 1024);
    const float4* b4 = (const float4*)gc2_b;
    const float4* w4 = (const float4*)gc3_W;
    int c = threadIdx.x;   // 256 threads x float4 = 1024
    float4 a = r0[c], b = r1[c], bb = b4[c], ww = w4[c];
    float s = fmaxf(a.x + b.x + bb.x, 0.f) * ww.x
            + fmaxf(a.y + b.y + bb.y, 0.f) * ww.y
            + fmaxf(a.z + b.z + bb.z, 0.f) * ww.z
            + fmaxf(a.w + b.w + bb.w, 0.f) * ww.w;
    s = blockReduceSum256(s);
    if (threadIdx.x == 0) vec[OFF_Y3 + i] = s;
}

// h3 from bf16 adj
__global__ void h3b_kernel(const unsigned short* __restrict__ adj_h,
                           const float* __restrict__ gc3_b, float* __restrict__ vec) {
    int i = blockIdx.x;
    const u16x4* rp = (const u16x4*)(adj_h + (size_t)i * 4096);
    const float* y3 = vec + OFF_Y3;
    float s = 0.f;
    for (int c = threadIdx.x; c < 1024; c += 256) {
        u16x4 v = rp[c];
        int k0 = c * 4;
        s += bh2f(v[0]) * y3[k0] + bh2f(v[1]) * y3[k0 + 1]
           + bh2f(v[2]) * y3[k0 + 2] + bh2f(v[3]) * y3[k0 + 3];
    }
    s = blockReduceSum256(s);
    if (threadIdx.x == 0) vec[OFF_H3 + i] = fmaxf(s + gc3_b[0], 0.f);
}

__global__ void h3_kernel(const float* __restrict__ adj, const float* __restrict__ gc3_b,
                          float* __restrict__ vec) {
    int i = blockIdx.x;
    const float* r = adj + (size_t)i * 4096;
    const float* y3 = vec + OFF_Y3;
    float s = 0.f;
    for (int k = threadIdx.x; k < 4096; k += 256) s += r[k] * y3[k];
    s = blockReduceSum256(s);
    if (threadIdx.x == 0) vec[OFF_H3 + i] = fmaxf(s + gc3_b[0], 0.f);
}

__global__ void gcn_kernel(const float* __restrict__ gcn512_W, const float* __restrict__ gcn512_b,
                           float* __restrict__ vec) {
    int j = blockIdx.x;
    const float* r = gcn512_W + (size_t)j * 4096;
    const float* h3 = vec + OFF_H3;
    float s = 0.f;
    for (int k = threadIdx.x; k < 4096; k += 256) s += r[k] * h3[k];
    s = blockReduceSum256(s);
    if (threadIdx.x == 0) vec[OFF_GCN + j] = fmaxf(s + gcn512_b[j], 0.f);
}

__global__ void x_kernel(const float* __restrict__ hidden_W, const float* __restrict__ hidden_b,
                         float* __restrict__ vec) {
    int j = blockIdx.x;
    const float* r = hidden_W + (size_t)j * 1536;
    const float* joint = vec;
    float s = 0.f;
    for (int k = threadIdx.x; k < 1536; k += 256) s += r[k] * joint[k];
    s = blockReduceSum256(s);
    if (threadIdx.x == 0) vec[OFF_X + j] = fmaxf(s + hidden_b[j], 0.f);
}

__global__ void out_kernel(const float* __restrict__ vec,
                           const float* __restrict__ critic_W, const float* __restrict__ critic_b,
                           const float* __restrict__ actor_W, const float* __restrict__ actor_b,
                           float* __restrict__ out) {
    const float* xv = vec + OFF_X;
    int w = threadIdx.x >> 6, l = threadIdx.x & 63;
    if (w >= 7) return;
    const float* row = (w == 0) ? critic_W : actor_W + (size_t)(w - 1) * 512;
    float s = 0.f;
    for (int q = l; q < 512; q += 64) s += xv[q] * row[q];
    #pragma unroll
    for (int o = 32; o > 0; o >>= 1) s += __shfl_down(s, o, 64);
    if (l == 0) out[w] = s + ((w == 0) ? critic_b[0] : actor_b[w - 1]);
}

// combine P1 split-K partials -> hi bf16 only
__global__ void combine_p1_kernel(const float* __restrict__ p1f,
                                  unsigned short* __restrict__ hi) {
    size_t i = (size_t)blockIdx.x * 256 + threadIdx.x;    // float4 index over 524288
    float4 a = ((const float4*)p1f)[i];
    float4 b = ((const float4*)(p1f + 2097152))[i];
    u16x4 hv;
    hv[0] = f2bh(a.x + b.x);
    hv[1] = f2bh(a.y + b.y);
    hv[2] = f2bh(a.z + b.z);
    hv[3] = f2bh(a.w + b.w);
    *(u16x4*)(hi + i * 4) = hv;
}

// ---------------- fused prep kernel: all converts + vec3, ILP-4 streaming ----------------
// grid: [0,4096) adj x4 | [4096,5376) emb x4 | [5376,5536) sw x4 |
// [5536,6048) w1T | [6048,7072) w2T | [7072,8608) vec3
__global__ void prep_kernel(const float* __restrict__ adj,
                            const float* __restrict__ all_embeds,
                            const float* __restrict__ semantic_W,
                            const float* __restrict__ gc1_W,
                            const float* __restrict__ gc2_W,
                            const float* __restrict__ frames,
                            const float* __restrict__ scores,
                            const float* __restrict__ word_embed,
                            const float* __restrict__ visual_W, const float* __restrict__ visual_b,
                            const float* __restrict__ semantic_b,
                            const float* __restrict__ score_W, const float* __restrict__ score_b,
                            unsigned short* __restrict__ adj_h,
                            unsigned short* __restrict__ emb_h, unsigned short* __restrict__ emb_l,
                            unsigned short* __restrict__ sw_h, unsigned short* __restrict__ sw_l,
                            unsigned short* __restrict__ w1t_h,
                            unsigned short* __restrict__ w2t_h,
                            float* __restrict__ vec) {
    __shared__ float tile[32][33];
    const int b = blockIdx.x, t = threadIdx.x;
    if (b < 4096) {
        // adj f32 -> bf16, 4 independent float4 loads per thread
        size_t base = (size_t)b * 1024 + t;
        float4 v[4];
        #pragma unroll
        for (int j = 0; j < 4; j++) v[j] = ((const float4*)adj)[base + j * 256];
        #pragma unroll
        for (int j = 0; j < 4; j++) {
            u16x4 h;
            h[0] = f2bh(v[j].x); h[1] = f2bh(v[j].y);
            h[2] = f2bh(v[j].z); h[3] = f2bh(v[j].w);
            *(u16x4*)(adj_h + (base + j * 256) * 4) = h;
        }
    } else if (b < 4096 + 1280) {
        // emb split (pad 300->320), 4 elems per thread, stride 327680
        size_t base = (size_t)(b - 4096) * 256 + t;
        float v[4];
        #pragma unroll
        for (int j = 0; j < 4; j++) {
            size_t i = base + (size_t)j * 327680;
            int r = (int)(i / 320), c = (int)(i % 320);
            v[j] = (c < 300) ? all_embeds[(size_t)r * 300 + c] : 0.f;
        }
        #pragma unroll
        for (int j = 0; j < 4; j++) {
            size_t i = base + (size_t)j * 327680;
            unsigned short h = f2bh(v[j]);
            emb_h[i] = h; emb_l[i] = f2bh(v[j] - bh2f(h));
        }
    } else if (b < 4096 + 1280 + 160) {
        // sw split (pad 300->320), 4 elems per thread, stride 40960
        size_t base = (size_t)(b - 4096 - 1280) * 256 + t;
        float v[4];
        #pragma unroll
        for (int j = 0; j < 4; j++) {
            size_t i = base + (size_t)j * 40960;
            int r = (int)(i / 320), c = (int)(i % 320);
            v[j] = (c < 300) ? semantic_W[(size_t)r * 300 + c] : 0.f;
        }
        #pragma unroll
        for (int j = 0; j < 4; j++) {
            size_t i = base + (size_t)j * 40960;
            unsigned short h = f2bh(v[j]);
            sw_h[i] = h; sw_l[i] = f2bh(v[j] - bh2f(h));
        }
    } else if (b < 4096 + 1280 + 160 + 512) {
        // w1T: src = gc1_W[512:,:] f32 [K=512, N=1024] -> [N,K] hi only
        int l2 = b - 4096 - 1280 - 160;
        const float* src = gc1_W + (size_t)512 * 1024;
        int kb = (l2 & 15) * 32, nb = (l2 >> 4) * 32;
        int tx = t & 31, ty = t >> 5;
        #pragma unroll
        for (int i = 0; i < 32; i += 8)
            tile[ty + i][tx] = src[(size_t)(kb + ty + i) * 1024 + nb + tx];
        __syncthreads();
        #pragma unroll
        for (int i = 0; i < 32; i += 8) {
            int n = nb + ty + i, k = kb + tx;
            w1t_h[(size_t)n * 512 + k] = f2bh(tile[tx][ty + i]);
        }
    } else if (b < 4096 + 1280 + 160 + 512 + 1024) {
        // w2T: gc2_W f32 [1024,1024] -> [N,K] hi
        int l2 = b - 4096 - 1280 - 160 - 512;
        int kb = (l2 & 31) * 32, nb = (l2 >> 5) * 32;
        int tx = t & 31, ty = t >> 5;
        #pragma unroll
        for (int i = 0; i < 32; i += 8)
            tile[ty + i][tx] = gc2_W[(size_t)(kb + ty + i) * 1024 + nb + tx];
        __syncthreads();
        #pragma unroll
        for (int i = 0; i < 32; i += 8) {
            int n = nb + ty + i, k = kb + tx;
            w2t_h[(size_t)n * 1024 + k] = f2bh(tile[tx][ty + i]);
        }
    } else {
        vec3_body(b - (4096 + 1280 + 160 + 512 + 1024), frames, scores, word_embed,
                  visual_W, visual_b, semantic_W, semantic_b, score_W, score_b, vec);
    }
}

// ---------------- staging helpers ----------------
template<int NCHP, int NJ>
__device__ __forceinline__ void stg_mat(const unsigned short* __restrict__ src, int ld, int r0,
                                        int k0, unsigned short* dst, int t) {
    #pragma unroll
    for (int j = 0; j < NJ; j++) {
        int c = j * 256 + t;
        int p = c / NCHP;
        int idx = c % NCHP;
        int row = idx >> 2;
        int gg = (idx & 3) ^ ((row >> 1) & 3);
        gload16(src + (size_t)(r0 + row) * ld + (k0 + p * 32 + gg * 8),
                dst + (size_t)(j * 256 + (t & ~63)) * 8);
    }
}

template<int ROWS>
__device__ __forceinline__ s16x8 rfrag(const unsigned short* rb, int row, int p, int g4) {
    int byte = (p * ROWS + row) * 64 + ((g4 ^ ((row >> 1) & 3)) << 4);
    return *(const s16x8*)((const char*)rb + byte);
}

// ---------------- 4-wave MFMA GEMM (round-4 proven structure) ----------------
template<int BM, int BK, int PROD, int WMODE, int RELU, int SPLITK>
__global__ __launch_bounds__(256) void mfma_g(
    const unsigned short* __restrict__ Ah, const unsigned short* __restrict__ Al,
    const unsigned short* __restrict__ Bh, const unsigned short* __restrict__ Bl,
    int K, int lda, int ldb,
    unsigned short* __restrict__ Ch, float* __restrict__ Cf, int ldc,
    const float* __restrict__ bias, const float* __restrict__ bias2)
{
    constexpr int A_USH = BM * BK;
    constexpr int B_USH = 64 * BK;
    constexpr int A_CH  = A_USH / 8;
    constexpr int B_CH  = B_USH / 8;
    constexpr int SLOT  = (PROD == 3) ? 2 * (A_USH + B_USH) : (A_USH + B_USH);
    constexpr int L     = ((A_CH + B_CH) / 256) * ((PROD == 3) ? 2 : 1);
    constexpr int FM    = BM / 32;
    __shared__ unsigned short lds[3 * SLOT];

    const int t = threadIdx.x;
    const int w = t >> 6, l = t & 63;
    const int r = l & 15, g4 = l >> 4;
    const int wr = (w >> 1) * (BM / 2);
    const int wc = (w & 1) * 32;

    const int gx = gridDim.x;
    const int nwg = gx * gridDim.y;
    int flat = blockIdx.y * gx + blockIdx.x;
    int swz = (flat & 7) * (nwg >> 3) + (flat >> 3);
    const int col0 = (swz % gx) * 64;
    const int row0 = (swz / gx) * BM;

    if constexpr (SPLITK) {
        int z = blockIdx.z;
        Ah += (size_t)z * K;
        Bh += (size_t)z * K;
        Cf += (size_t)z * (size_t)nwg * (BM * 64);
    }

    f32x4 acc[FM][2];
    #pragma unroll
    for (int a = 0; a < FM; a++)
        #pragma unroll
        for (int b = 0; b < 2; b++) acc[a][b] = (f32x4){0.f, 0.f, 0.f, 0.f};

    auto stage = [&](int slot, int k0) {
        unsigned short* base = lds + slot * SLOT;
        stg_mat<BM * 4, A_CH / 256>(Ah, lda, row0, k0, base, t);
        stg_mat<256,    B_CH / 256>(Bh, ldb, col0, k0, base + A_USH, t);
        if constexpr (PROD == 3) {
            stg_mat<256,    B_CH / 256>(Bl, ldb, col0, k0, base + A_USH + B_USH, t);
            stg_mat<BM * 4, A_CH / 256>(Al, lda, row0, k0, base + A_USH + 2 * B_USH, t);
        }
    };

    const int T = K / BK;
    stage(0, 0);
    stage(1, BK);

    for (int tt = 0; tt < T; ++tt) {
        __builtin_amdgcn_s_barrier();
        if (tt + 2 < T) {
            stage((tt + 2) % 3, (tt + 2) * BK);
            if constexpr (L == 4) asm volatile("s_waitcnt vmcnt(8)" ::: "memory");
            else                  asm volatile("s_waitcnt vmcnt(12)" ::: "memory");
        } else if (tt + 1 < T) {
            if constexpr (L == 4) asm volatile("s_waitcnt vmcnt(4)" ::: "memory");
            else                  asm volatile("s_waitcnt vmcnt(6)" ::: "memory");
        } else {
            asm volatile("s_waitcnt vmcnt(0)" ::: "memory");
        }
        __builtin_amdgcn_s_barrier();

        const unsigned short* base = lds + (tt % 3) * SLOT;
        #pragma unroll
        for (int kk = 0; kk < BK / 32; kk++) {
            s16x8 a[FM], bb[2], alr[FM], blr[2];
            #pragma unroll
            for (int f = 0; f < FM; f++) a[f] = rfrag<BM>(base, wr + f * 16 + r, kk, g4);
            #pragma unroll
            for (int f = 0; f < 2; f++) bb[f] = rfrag<64>(base + A_USH, wc + f * 16 + r, kk, g4);
            if constexpr (PROD == 3) {
                #pragma unroll
                for (int f = 0; f < 2; f++) blr[f] = rfrag<64>(base + A_USH + B_USH, wc + f * 16 + r, kk, g4);
                #pragma unroll
                for (int f = 0; f < FM; f++) alr[f] = rfrag<BM>(base + A_USH + 2 * B_USH, wr + f * 16 + r, kk, g4);
            }
            __builtin_amdgcn_s_setprio(1);
            #pragma unroll
            for (int fm = 0; fm < FM; fm++)
                #pragma unroll
                for (int fn = 0; fn < 2; fn++) {
                    acc[fm][fn] = MF(a[fm], bb[fn], acc[fm][fn]);
                    if constexpr (PROD == 3) {
                        acc[fm][fn] = MF(a[fm], blr[fn], acc[fm][fn]);
                        acc[fm][fn] = MF(alr[fm], bb[fn], acc[fm][fn]);
                    }
                }
            __builtin_amdgcn_s_setprio(0);
        }
    }

    // epilogue (C/D: col = lane&15, row = 4*(lane>>4)+i — m89-verified)
    #pragma unroll
    for (int fn = 0; fn < 2; fn++) {
        int n = col0 + wc + fn * 16 + r;
        float bn = bias ? bias[n] : 0.f;
        if (bias2) bn += bias2[n];
        #pragma unroll
        for (int fm = 0; fm < FM; fm++) {
            int m0 = row0 + wr + fm * 16 + g4 * 4;
            f32x4 v = acc[fm][fn];
            if constexpr (WMODE == 4) {
                u16x4 hv;
                #pragma unroll
                for (int i = 0; i < 4; i++) {
                    float x = v[i] + bn;
                    if (RELU) x = fmaxf(x, 0.f);
                    hv[i] = f2bh(x);
                }
                *(u16x4*)(Ch + (size_t)n * ldc + m0) = hv;
            } else if constexpr (WMODE == 6) {
                #pragma unroll
                for (int i = 0; i < 4; i++) {
                    float x = v[i] + bn;
                    if (RELU) x = fmaxf(x, 0.f);
                    Cf[(size_t)(m0 + i) * ldc + n] = x;
                }
            } else {  // WMODE 3: hi bf16 C[m][n]
                #pragma unroll
                for (int i = 0; i < 4; i++) {
                    float x = v[i] + bn;
                    if (RELU) x = fmaxf(x, 0.f);
                    Ch[(size_t)(m0 + i) * ldc + n] = f2bh(x);
                }
            }
        }
    }
}

// ---------------- 4-wave SQUARE-tile GEMM: 128x128, wave 64x64, BK=32, ring-3, split-K ----
__global__ __launch_bounds__(256) void mfma_sq(
    const unsigned short* __restrict__ Ah,
    const unsigned short* __restrict__ Bh,
    int Kc, int lda, int ldb,
    float* __restrict__ Cf, int ldc)
{
    constexpr int A_USH = 128 * 32;           // 4096 ush
    constexpr int SLOT  = 2 * A_USH;          // 8192 ush = 16 KB
    __shared__ unsigned short lds[3 * SLOT];

    const int t = threadIdx.x;
    const int w = t >> 6, l = t & 63;
    const int r = l & 15, g4 = l >> 4;
    const int wr = (w >> 1) * 64, wc = (w & 1) * 64;

    const int gx = gridDim.x;
    const int nwg = gx * gridDim.y;
    int flat = blockIdx.y * gx + blockIdx.x;
    int swz = (flat & 7) * (nwg >> 3) + (flat >> 3);
    const int col0 = (swz % gx) * 128;
    const int row0 = (swz / gx) * 128;

    const int z = blockIdx.z;
    Ah += (size_t)z * Kc;
    Bh += (size_t)z * Kc;
    Cf += (size_t)z * 4194304;

    f32x4 acc[4][4];
    #pragma unroll
    for (int a = 0; a < 4; a++)
        #pragma unroll
        for (int b = 0; b < 4; b++) acc[a][b] = (f32x4){0.f, 0.f, 0.f, 0.f};

    auto stage = [&](int slot, int k0) {
        unsigned short* base = lds + slot * SLOT;
        stg_mat<512, 2>(Ah, lda, row0, k0, base, t);
        stg_mat<512, 2>(Bh, ldb, col0, k0, base + A_USH, t);
    };

    const int T = Kc >> 5;
    stage(0, 0);
    stage(1, 32);

    for (int tt = 0; tt < T; ++tt) {
        __builtin_amdgcn_s_barrier();
        if (tt + 2 < T) {
            stage((tt + 2) % 3, (tt + 2) * 32);
            asm volatile("s_waitcnt vmcnt(8)" ::: "memory");
        } else if (tt + 1 < T) {
            asm volatile("s_waitcnt vmcnt(4)" ::: "memory");
        } else {
            asm volatile("s_waitcnt vmcnt(0)" ::: "memory");
        }
        __builtin_amdgcn_s_barrier();

        const unsigned short* base = lds + (tt % 3) * SLOT;
        s16x8 a[4], bb[4];
        #pragma unroll
        for (int f = 0; f < 4; f++) a[f] = rfrag<128>(base, wr + f * 16 + r, 0, g4);
        #pragma unroll
        for (int f = 0; f < 4; f++) bb[f] = rfrag<128>(base + A_USH, wc + f * 16 + r, 0, g4);
        __builtin_amdgcn_s_setprio(1);
        #pragma unroll
        for (int fm = 0; fm < 4; fm++)
            #pragma unroll
            for (int fn = 0; fn < 4; fn++)
                acc[fm][fn] = MF(a[fm], bb[fn], acc[fm][fn]);
        __builtin_amdgcn_s_setprio(0);
    }

    // epilogue: f32 partials
    #pragma unroll
    for (int fn = 0; fn < 4; fn++) {
        int n = col0 + wc + fn * 16 + r;
        #pragma unroll
        for (int fm = 0; fm < 4; fm++) {
            int m0 = row0 + wr + fm * 16 + g4 * 4;
            f32x4 v = acc[fm][fn];
            #pragma unroll
            for (int i = 0; i < 4; i++)
                Cf[(size_t)(m0 + i) * ldc + n] = v[i];
        }
    }
}

// ---------------- fallback f32 tiled GEMM (round-1, proven) ----------------
template<int TRANSB>
__global__ __launch_bounds__(256) void gemm_f32_128(
    const float* __restrict__ A, const float* __restrict__ B, float* __restrict__ C,
    int M, int N, int K, int lda, int ldb,
    const float* __restrict__ bias, const float* __restrict__ vrow, int do_relu)
{
    constexpr int BM = 128, BN = 128, BK = 16;
    __shared__ float As[BK][BM + 4];
    __shared__ float Bs[BK][BN + 4];
    const int t = threadIdx.x;
    const int w = t >> 6, l = t & 63;
    const int cx = (w & 1) * 8 + (l & 7);
    const int cy = (w >> 1) * 8 + (l >> 3);
    const int row0 = blockIdx.y * BM;
    const int col0 = blockIdx.x * BN;

    float acc[8][8];
    #pragma unroll
    for (int i = 0; i < 8; i++)
        #pragma unroll
        for (int j = 0; j < 8; j++) acc[i][j] = 0.f;

    const int ka = t & 15;
    const int ma = t >> 4;

    for (int k0 = 0; k0 < K; k0 += BK) {
        #pragma unroll
        for (int i = 0; i < 8; i++) {
            int m = ma + i * 16;
            int gk = k0 + ka;
            float v = 0.f;
            if (gk < K) v = A[(size_t)(row0 + m) * lda + gk];
            As[ka][m] = v;
        }
        if (TRANSB) {
            #pragma unroll
            for (int i = 0; i < 8; i++) {
                int n = ma + i * 16;
                int gk = k0 + ka;
                float v = 0.f;
                if (gk < K) v = B[(size_t)(col0 + n) * ldb + gk];
                Bs[ka][n] = v;
            }
        } else {
            const int nb = t & 127;
            const int kb = t >> 7;
            #pragma unroll
            for (int i = 0; i < 8; i++) {
                int kk = kb + i * 2;
                int gk = k0 + kk;
                float v = 0.f;
                if (gk < K) v = B[(size_t)gk * ldb + col0 + nb];
                Bs[kk][nb] = v;
            }
        }
        __syncthreads();
        #pragma unroll
        for (int kk = 0; kk < BK; kk++) {
            float a[8], bb[8];
            *(float4*)&a[0]  = *(const float4*)&As[kk][cy * 8];
            *(float4*)&a[4]  = *(const float4*)&As[kk][cy * 8 + 4];
            *(float4*)&bb[0] = *(const float4*)&Bs[kk][cx * 8];
            *(float4*)&bb[4] = *(const float4*)&Bs[kk][cx * 8 + 4];
            #pragma unroll
            for (int i = 0; i < 8; i++)
                #pragma unroll
                for (int j = 0; j < 8; j++)
                    acc[i][j] = fmaf(a[i], bb[j], acc[i][j]);
        }
        __syncthreads();
    }

    #pragma unroll
    for (int i = 0; i < 8; i++) {
        int rr = row0 + cy * 8 + i;
        float vv[8];
        #pragma unroll
        for (int j = 0; j < 8; j++) {
            int c = col0 + cx * 8 + j;
            float v = acc[i][j];
            if (vrow) v += vrow[c];
            if (bias) v += bias[c];
            if (do_relu) v = fmaxf(v, 0.f);
            vv[j] = v;
        }
        float* cp = C + (size_t)rr * N + col0 + cx * 8;
        *(float4*)cp       = *(float4*)&vv[0];
        *(float4*)(cp + 4) = *(float4*)&vv[4];
    }
}

// ---------------- host launcher ----------------
extern "C" void kernel_launch(void* const* d_in, const int* in_sizes, int n_in,
                              void* d_out, int out_size, void* d_ws, size_t ws_size,
                              hipStream_t stream) {
    const float* frames     = (const float*)d_in[0];
    const float* scores     = (const float*)d_in[1];
    const float* word_embed = (const float*)d_in[2];
    const float* all_embeds = (const float*)d_in[3];
    const float* adj        = (const float*)d_in[4];
    const float* visual_W   = (const float*)d_in[5];
    const float* visual_b   = (const float*)d_in[6];
    const float* semantic_W = (const float*)d_in[7];
    const float* semantic_b = (const float*)d_in[8];
    const float* score_W    = (const float*)d_in[9];
    const float* score_b    = (const float*)d_in[10];
    const float* gc1_W      = (const float*)d_in[11];
    const float* gc1_b      = (const float*)d_in[12];
    const float* gc2_W      = (const float*)d_in[13];
    const float* gc2_b      = (const float*)d_in[14];
    const float* gc3_W      = (const float*)d_in[15];
    const float* gc3_b      = (const float*)d_in[16];
    const float* gcn512_W   = (const float*)d_in[17];
    const float* gcn512_b   = (const float*)d_in[18];
    const float* hidden_W   = (const float*)d_in[19];
    const float* hidden_b   = (const float*)d_in[20];
    const float* critic_W   = (const float*)d_in[21];
    const float* critic_b   = (const float*)d_in[22];
    const float* actor_W    = (const float*)d_in[23];
    const float* actor_b    = (const float*)d_in[24];

    float* out = (float*)d_out;

    if (ws_size >= FAST_WS) {
        char* wsb = (char*)d_ws;
        unsigned short* adj_h = (unsigned short*)(wsb + F_ADJH);
        unsigned short* emb_h = (unsigned short*)(wsb + F_EMB_H);
        unsigned short* emb_l = (unsigned short*)(wsb + F_EMB_L);
        unsigned short* sw_h  = (unsigned short*)(wsb + F_SW_H);
        unsigned short* sw_l  = (unsigned short*)(wsb + F_SW_L);
        unsigned short* w1t_h = (unsigned short*)(wsb + F_W1T_H);
        unsigned short* w2t_h = (unsigned short*)(wsb + F_W2T_H);
        unsigned short* emT   = (unsigned short*)(wsb + F_EMT);
        float*          p1f   = (float*)(wsb + F_P1F);
        unsigned short* p1_h  = (unsigned short*)(wsb + F_P1H);
        unsigned short* h1    = (unsigned short*)(wsb + F_H1);
        unsigned short* y2t   = (unsigned short*)(wsb + F_Y2T);
        float*          p7f   = (float*)(wsb + F_P7F);
        float*          vec   = (float*)(wsb + F_VEC);

        // 1. prep: all converts + vec3 (ILP-4 streaming)
        prep_kernel<<<4096 + 1280 + 160 + 512 + 1024 + 1536, 256, 0, stream>>>(
            adj, all_embeds, semantic_W, gc1_W, gc2_W,
            frames, scores, word_embed, visual_W, visual_b, semantic_b, score_W, score_b,
            adj_h, emb_h, emb_l, sw_h, sw_l, w1t_h, w2t_h, vec);
        // 2. vrow = s512 @ gc1_W[:512,:]
        vrow_kernel<<<8, 256, 0, stream>>>(gc1_W, vec);
        // 3. emT = relu(all_embeds @ semantic_W^T + b)^T  hi [512,4096], K=320, PROD=3
        mfma_g<64, 32, 3, 4, 1, 0><<<dim3(8, 64), 256, 0, stream>>>(
            emb_h, emb_l, sw_h, sw_l, 320, 320, 320,
            emT, nullptr, 4096, semantic_b, nullptr);
        // 4. P1 partials = adj @ em  f32, split-K x2  [4096,512]
        mfma_g<128, 64, 1, 6, 0, 1><<<dim3(8, 32, 2), 256, 0, stream>>>(
            adj_h, nullptr, emT, nullptr, 2048, 4096, 4096,
            nullptr, p1f, 512, nullptr, nullptr);
        // 4b. combine partials -> p1 hi
        combine_p1_kernel<<<2048, 256, 0, stream>>>(p1f, p1_h);
        // 5. h1 = relu(P1_hi @ W1'_hi + vrow + b1)  hi [4096,1024], K=512, PROD=1
        mfma_g<128, 64, 1, 3, 1, 0><<<dim3(16, 32), 256, 0, stream>>>(
            p1_h, nullptr, w1t_h, nullptr, 512, 512, 512,
            h1, nullptr, 1024, gc1_b, vec + OFF_VROW);
        // 6. y2t = (h1 @ gc2_W)^T  hi [1024,4096], K=1024
        mfma_g<128, 64, 1, 4, 0, 0><<<dim3(16, 32), 256, 0, stream>>>(
            h1, nullptr, w2t_h, nullptr, 1024, 1024, 1024,
            y2t, nullptr, 4096, nullptr, nullptr);
        // 7. p7f partials = adj @ Y2  f32, square tiles, split-K x2  [4096,1024]
        mfma_sq<<<dim3(8, 32, 2), 256, 0, stream>>>(
            adj_h, y2t, 2048, 4096, 4096, p7f, 1024);
        // 7b. y3[i] = sum_j relu(p7f0+p7f1+b2)[i,j] * gc3_W[j]
        h2y3_kernel<<<4096, 256, 0, stream>>>(p7f, gc2_b, gc3_W, vec);
        // 8-11. tail
        h3b_kernel<<<4096, 256, 0, stream>>>(adj_h, gc3_b, vec);
        gcn_kernel<<<512, 256, 0, stream>>>(gcn512_W, gcn512_b, vec);
        x_kernel<<<512, 256, 0, stream>>>(hidden_W, hidden_b, vec);
        out_kernel<<<1, 512, 0, stream>>>(vec, critic_W, critic_b, actor_W, actor_b, out);
    } else {
        // fallback f32 path (round-1, proven within 50.4 MB)
        float* ws = (float*)d_ws;
        float* em = ws + OFF_BUF0;
        float* Y1 = ws + OFF_BUF1;
        float* H1 = ws + OFF_BUF2;
        float* Y2 = ws + OFF_BUF1;
        float* H2 = ws + OFF_BUF0;

        vec3_kernel<<<1536, 256, 0, stream>>>(frames, scores, word_embed,
                                              visual_W, visual_b, semantic_W, semantic_b,
                                              score_W, score_b, ws);
        vrow_kernel<<<8, 256, 0, stream>>>(gc1_W, ws);
        gemm_f32_128<1><<<dim3(512 / 128, 4096 / 128), 256, 0, stream>>>(
            all_embeds, semantic_W, em, 4096, 512, 300, 300, 300, semantic_b, nullptr, 1);
        gemm_f32_128<0><<<dim3(1024 / 128, 4096 / 128), 256, 0, stream>>>(
            em, gc1_W + (size_t)512 * 1024, Y1, 4096, 1024, 512, 512, 1024,
            nullptr, ws + OFF_VROW, 0);
        gemm_f32_128<0><<<dim3(1024 / 128, 4096 / 128), 256, 0, stream>>>(
            adj, Y1, H1, 4096, 1024, 4096, 4096, 1024, gc1_b, nullptr, 1);
        gemm_f32_128<0><<<dim3(1024 / 128, 4096 / 128), 256, 0, stream>>>(
            H1, gc2_W, Y2, 4096, 1024, 1024, 1024, 1024, nullptr, nullptr, 0);
        gemm_f32_128<0><<<dim3(1024 / 128, 4096 / 128), 256, 0, stream>>>(
            adj, Y2, H2, 4096, 1024, 4096, 4096, 1024, gc2_b, nullptr, 1);
        y3_kernel<<<4096, 256, 0, stream>>>(H2, gc3_W, ws);
        h3_kernel<<<4096, 256, 0, stream>>>(adj, gc3_b, ws);
        gcn_kernel<<<512, 256, 0, stream>>>(gcn512_W, gcn512_b, ws);
        x_kernel<<<512, 256, 0, stream>>>(hidden_W, hidden_b, ws);
        out_kernel<<<1, 512, 0, stream>>>(ws, critic_W, critic_b, actor_W, actor_b, out);
    }

    (void)in_sizes; (void)n_in; (void)out_size;
}